// Round 4
// baseline (5581.828 us; speedup 1.0000x reference)
//
#include <hip/hip_runtime.h>
#include <stdint.h>

#define B_ 128
#define T_ 256
#define F_ 128
#define NCAT_ 32
#define CARD_ 16
#define E_ 8
#define H_ 512
#define INLEN_ 352
#define NCONT_ 96

typedef __bf16 bf16x8 __attribute__((ext_vector_type(8)));
typedef float f32x4 __attribute__((ext_vector_type(4)));
typedef unsigned short ushortx8 __attribute__((ext_vector_type(8)));

__device__ __forceinline__ unsigned short f2bf(float f) {
  unsigned int u = __float_as_uint(f);
  u += 0x7fffu + ((u >> 16) & 1u);   // RNE
  return (unsigned short)(u >> 16);
}
__device__ __forceinline__ float sigm(float x) { return 1.0f / (1.0f + __expf(-x)); }
__device__ __forceinline__ float tanhf_(float x) {
  float a = fabsf(x);
  float e = __expf(-2.0f * a);
  float t = (1.0f - e) / (1.0f + e);
  return x < 0.0f ? -t : t;
}

// ---------------- init: zero the 4 tagged h slots (tag 0 == h_{-1} = 0) ----------------
__global__ void k_initH(unsigned int* Htag) {
  __hip_atomic_store(&Htag[blockIdx.x * 256 + threadIdx.x], 0u, __ATOMIC_RELAXED,
                     __HIP_MEMORY_SCOPE_AGENT);
}

// ---------------- prep: W_in transposed -> bf16 (512 x 352) ----------------
__global__ void k_prep(const float* __restrict__ W_in, unsigned short* __restrict__ W_inT) {
  int id = blockIdx.x * 256 + threadIdx.x;
  if (id < 512 * INLEN_) {
    int n = id / INLEN_;
    int k = id - n * INLEN_;
    W_inT[id] = f2bf(W_in[k * 512 + n]);
  }
}

// ---------------- features: FEAT[t*128+b][352] bf16 ----------------
__global__ void k_feat(const int* __restrict__ unscaled, const float* __restrict__ scaled,
                       const float* __restrict__ emb, unsigned short* __restrict__ FEAT) {
  int row = blockIdx.x * 4 + (threadIdx.x >> 6);
  int t = row >> 7, b = row & 127;
  const int base = (b * T_ + t) * F_;
  for (int jj = (threadIdx.x & 63); jj < INLEN_; jj += 64) {
    int ci = jj / 11;
    int pos = jj - ci * 11;
    float v;
    if (pos < 8) {
      int cid = unscaled[base + 4 * ci];
      v = emb[(ci * CARD_ + cid) * E_ + pos];
    } else {
      v = scaled[base + 4 * ci + 1 + (pos - 8)];
    }
    FEAT[row * INLEN_ + jj] = f2bf(v);
  }
}

// ---------------- GEMM1: X = relu(FEAT @ W_in + b_in), bf16 out ----------------
__global__ __launch_bounds__(256) void k_gemm1(const unsigned short* __restrict__ FEAT,
                                               const unsigned short* __restrict__ W_inT,
                                               const float* __restrict__ b_in,
                                               unsigned short* __restrict__ X) {
  __shared__ __align__(16) unsigned short As[128 * 40];
  __shared__ __align__(16) unsigned short Bs[128 * 40];
  const int tid = threadIdx.x;
  const int Mtile = blockIdx.x >> 2;
  const int N0 = (blockIdx.x & 3) * 128;
  const int wv = tid >> 6, ln = tid & 63;
  const int lrow = ln & 15, lq = ln >> 4;
  f32x4 acc[2][8];
#pragma unroll
  for (int i = 0; i < 2; ++i)
#pragma unroll
    for (int j = 0; j < 8; ++j) acc[i][j] = (f32x4){0.f, 0.f, 0.f, 0.f};

  for (int kc = 0; kc < 11; ++kc) {
    int k0 = kc * 32;
#pragma unroll
    for (int i = 0; i < 2; ++i) {
      int c = i * 256 + tid;
      int row = c >> 2;
      int col = (c & 3) * 8;
      uint4 va = *(const uint4*)&FEAT[(Mtile * 128 + row) * INLEN_ + k0 + col];
      *(uint4*)&As[row * 40 + col] = va;
      uint4 vb = *(const uint4*)&W_inT[(N0 + row) * INLEN_ + k0 + col];
      *(uint4*)&Bs[row * 40 + col] = vb;
    }
    __syncthreads();
    bf16x8 af[2];
#pragma unroll
    for (int mt = 0; mt < 2; ++mt) {
      int r = wv * 32 + mt * 16 + lrow;
      af[mt] = __builtin_bit_cast(bf16x8, *(const ushortx8*)&As[r * 40 + lq * 8]);
    }
#pragma unroll
    for (int ntl = 0; ntl < 8; ++ntl) {
      bf16x8 bf = __builtin_bit_cast(bf16x8, *(const ushortx8*)&Bs[(ntl * 16 + lrow) * 40 + lq * 8]);
      acc[0][ntl] = __builtin_amdgcn_mfma_f32_16x16x32_bf16(af[0], bf, acc[0][ntl], 0, 0, 0);
      acc[1][ntl] = __builtin_amdgcn_mfma_f32_16x16x32_bf16(af[1], bf, acc[1][ntl], 0, 0, 0);
    }
    __syncthreads();
  }
#pragma unroll
  for (int mt = 0; mt < 2; ++mt)
#pragma unroll
    for (int ntl = 0; ntl < 8; ++ntl) {
      int n = N0 + ntl * 16 + lrow;
      float bias = b_in[n];
#pragma unroll
      for (int r = 0; r < 4; ++r) {
        int row = Mtile * 128 + wv * 32 + mt * 16 + lq * 4 + r;
        float v = acc[mt][ntl][r] + bias;
        v = v > 0.0f ? v : 0.0f;
        X[row * H_ + n] = f2bf(v);
      }
    }
}

// ---------------- persistent LSTM: 8 groups x 16 blocks, 512 thr ----------------
// Protocol: tagged data words at agent scope (MALL coherence point).
//   word = (tag16 << 16) | bf16, tag = t+1. The data IS the flag: producer
//   stores (coalesced, 16B/lane) and moves on (NO drain, NO flag); consumer's
//   speculative load doubles as the poll; retry rounds are 1 pipelined RTT.
// Own chunk goes through LDS directly, so blocks never wait on their own stores.
// Depth-2 ping-pong WAR-safe: overwrite at t+2 is issued only after validating
// peers' t+1 tags, which happens-after every peer's t-read completed.
// Tag<=256 never wraps; zero-init = tag 0 = h_{-1}=0.
__device__ __forceinline__ void stageX(unsigned short* dst, const unsigned short* src, int tid) {
#pragma unroll
  for (int i = 0; i < 2; ++i) {
    int c = i * 512 + tid;
    int row = c >> 6;
    int col = (c & 63) * 8;
    uint4 v = *(const uint4*)&src[row * H_ + col];
    *(uint4*)&dst[row * 520 + col] = v;
  }
}

__device__ __forceinline__ void load8(unsigned long long vv[8], const unsigned long long* p) {
#pragma unroll
  for (int i = 0; i < 8; ++i)
    vv[i] = __hip_atomic_load(p + i, __ATOMIC_RELAXED, __HIP_MEMORY_SCOPE_AGENT);
}
__device__ __forceinline__ bool check8(const unsigned long long vv[8], unsigned int exp) {
  unsigned int d = 0;
#pragma unroll
  for (int i = 0; i < 8; ++i) {
    d |= (((unsigned int)(vv[i] >> 16)) & 0xFFFFu) ^ exp;
    d |= ((unsigned int)(vv[i] >> 48)) ^ exp;
  }
  return d == 0;
}
__device__ __forceinline__ void strip8(const unsigned long long vv[8], unsigned short* hS,
                                       int base) {
#pragma unroll
  for (int i = 0; i < 8; ++i) {
    unsigned int w = ((unsigned int)vv[i] & 0xFFFFu) | (((unsigned int)(vv[i] >> 32)) << 16);
    *(unsigned int*)&hS[base + 2 * i] = w;
  }
}
__device__ __forceinline__ void consume(unsigned long long vv[8], const unsigned long long* src,
                                        unsigned int exp, bool skip, unsigned short* hS,
                                        int ldsOff, int& guard) {
  bool ok = skip || check8(vv, exp);
  while (!__all((int)ok)) {
    if (!ok) {
      load8(vv, src);
      ok = check8(vv, exp);
    }
    if (++guard > 1000000) break;   // bail -> wrong answer instead of hang
  }
  if (!skip) strip8(vv, hS, ldsOff);
}

__global__ __launch_bounds__(512, 1) void k_lstm(
    const float* __restrict__ Wih0, const float* __restrict__ Whh0,
    const float* __restrict__ bih0, const float* __restrict__ bhh0,
    const float* __restrict__ Wih1, const float* __restrict__ Whh1,
    const float* __restrict__ bih1, const float* __restrict__ bhh1,
    const unsigned short* __restrict__ X, unsigned int* __restrict__ Htag,
    float* __restrict__ out_h, float* __restrict__ out_c) {
  __shared__ __align__(16) unsigned short hS[16 * 520];
  __shared__ __align__(16) unsigned short xS[16 * 520];
  __shared__ __align__(16) float gS[128 * 20];
  __shared__ float b0cS[128], b1cS[128];

  const int tid = threadIdx.x;
  const int group = blockIdx.x & 7;    // XCD-packed (r2: halves FETCH via X dedup in L2)
  const int bc = blockIdx.x >> 3;     // 0..15 : h-cols j0..j0+31
  const int j0 = bc * 32;
  const int r0 = group * 16;
  const int wv = tid >> 6, ln = tid & 63;
  const int lrow = ln & 15, lq = ln >> 4;
  const int n_local = wv * 16 + lrow;                              // 0..127 gate-col in block
  const int gcol = ((n_local >> 5) << 9) + j0 + (n_local & 31);    // gate*512 + hcol

  // one-time: weight B-fragments in registers (bf16), combined biases in LDS
  bf16x8 Bf0[32], Bf1[16];
  {
    const float* s0 = Wih0 + gcol * H_;
    const float* s1 = Whh0 + gcol * H_;
#pragma unroll
    for (int ks = 0; ks < 32; ++ks) {
      int k = (ks & 15) * 32 + lq * 8;
      const float* s = (ks < 16) ? (s0 + k) : (s1 + k);
      ushortx8 u;
#pragma unroll
      for (int j = 0; j < 8; ++j) u[j] = f2bf(s[j]);
      Bf0[ks] = __builtin_bit_cast(bf16x8, u);
    }
    const float* sa = Wih1 + gcol * H_;
    const float* sb = Whh1 + gcol * H_;
#pragma unroll
    for (int ks = 0; ks < 16; ++ks) {
      int k = ks * 32 + lq * 8;
      ushortx8 u;
#pragma unroll
      for (int j = 0; j < 8; ++j) u[j] = f2bf(sa[k + j] + sb[k + j]);
      Bf1[ks] = __builtin_bit_cast(bf16x8, u);
    }
  }
  if (tid < 128) {
    int g2 = ((tid >> 5) << 9) + j0 + (tid & 31);
    b0cS[tid] = bih0[g2] + bhh0[g2];
    b1cS[tid] = bih1[g2] + bhh1[g2];
  }

  unsigned int* const HA0 = Htag;             // cell0 h, slot 0
  unsigned int* const HA1 = Htag + 65536;     // cell0 h, slot 1
  unsigned int* const HB0 = Htag + 131072;    // cell1 h, slot 0
  unsigned int* const HB1 = Htag + 196608;    // cell1 h, slot 1

  const int eb = tid & 15, ej = tid >> 4;   // elementwise ownership: row eb, h-col j0+ej
  const int fragOff = lrow * 520 + lq * 8;
  const int lnm = ln & 15;
  // consume mapping: each thread owns one 64B line (8 u64 = 16 tagged cols)
  const int crow = tid >> 5;                        // 0..15
  const int cb = tid & 31;                          // 16-col block
  const bool skip = ((cb >> 1) == bc);              // own chunk -> comes via LDS
  const int srcOff = (r0 + crow) * 256 + cb * 8;    // u64 units
  const int ldsOff = crow * 520 + cb * 16;          // short units
  float c_reg = 0.0f, cp_v = 0.0f;
  int guard = 0;

  stageX(xS, X + (0 * B_ + r0) * H_, tid);   // preload X_0
  __syncthreads();

#pragma unroll 1
  for (int t = 0; t < T_; ++t) {
    // ======== cell 0 ========
    const unsigned long long* src0 =
        (const unsigned long long*)(((t + 1) & 1) ? HB1 : HB0) + srcOff;
    unsigned long long vv[8];
    if (!skip) load8(vv, src0);   // speculative round-1, overlaps x-MFMAs
    f32x4 acc = (f32x4){0.f, 0.f, 0.f, 0.f};
#pragma unroll
    for (int ks = 0; ks < 16; ++ks) {
      bf16x8 a = __builtin_bit_cast(bf16x8, *(const ushortx8*)&xS[fragOff + ks * 32]);
      acc = __builtin_amdgcn_mfma_f32_16x16x32_bf16(a, Bf0[ks], acc, 0, 0, 0);
    }
    consume(vv, src0, (unsigned int)t, skip, hS, ldsOff, guard);
    __syncthreads();
#pragma unroll
    for (int ks = 0; ks < 16; ++ks) {
      bf16x8 a = __builtin_bit_cast(bf16x8, *(const ushortx8*)&hS[fragOff + ks * 32]);
      acc = __builtin_amdgcn_mfma_f32_16x16x32_bf16(a, Bf0[16 + ks], acc, 0, 0, 0);
    }
    *(f32x4*)&gS[n_local * 20 + lq * 4] = acc;
    __syncthreads();
    {
      float iv = gS[(ej) * 20 + eb] + b0cS[ej];
      float fv = gS[(32 + ej) * 20 + eb] + b0cS[32 + ej];
      float gv = gS[(64 + ej) * 20 + eb] + b0cS[64 + ej];
      float ov = gS[(96 + ej) * 20 + eb] + b0cS[96 + ej];
      cp_v = sigm(fv) * c_reg + sigm(iv) * tanhf_(gv);
      float hv = sigm(ov) * tanhf_(cp_v);
      hS[eb * 520 + j0 + ej] = f2bf(hv);   // own chunk straight to LDS
      // coalesced tagged publish: 16 lanes/wave x 2 u64 (16B contiguous)
      float p0 = __shfl(hv, lnm, 64);
      float p1 = __shfl(hv, lnm + 16, 64);
      float p2 = __shfl(hv, lnm + 32, 64);
      float p3 = __shfl(hv, lnm + 48, 64);
      if (ln < 16) {
        unsigned int tg = (unsigned int)(t + 1) << 16;
        unsigned long long q01 = ((unsigned long long)(tg | f2bf(p0))) |
                                 (((unsigned long long)(tg | f2bf(p1))) << 32);
        unsigned long long q23 = ((unsigned long long)(tg | f2bf(p2))) |
                                 (((unsigned long long)(tg | f2bf(p3))) << 32);
        unsigned long long* d = (unsigned long long*)(((t & 1) ? HA1 : HA0) +
                                                      (r0 + lnm) * 512 + j0 + wv * 4);
        __hip_atomic_store(d, q01, __ATOMIC_RELAXED, __HIP_MEMORY_SCOPE_AGENT);
        __hip_atomic_store(d + 1, q23, __ATOMIC_RELAXED, __HIP_MEMORY_SCOPE_AGENT);
      }
    }
    // no drain, no flag, no barrier: tags carry readiness

    // ======== cell 1 ========
    if (t + 1 < T_) stageX(xS, X + ((t + 1) * B_ + r0) * H_, tid);   // prefetch next X
    const unsigned long long* src1 =
        (const unsigned long long*)((t & 1) ? HA1 : HA0) + srcOff;
    if (!skip) load8(vv, src1);
    consume(vv, src1, (unsigned int)(t + 1), skip, hS, ldsOff, guard);
    __syncthreads();
    acc = (f32x4){0.f, 0.f, 0.f, 0.f};
#pragma unroll
    for (int ks = 0; ks < 16; ++ks) {
      bf16x8 a = __builtin_bit_cast(bf16x8, *(const ushortx8*)&hS[fragOff + ks * 32]);
      acc = __builtin_amdgcn_mfma_f32_16x16x32_bf16(a, Bf1[ks], acc, 0, 0, 0);
    }
    *(f32x4*)&gS[n_local * 20 + lq * 4] = acc;
    __syncthreads();
    {
      float iv = gS[(ej) * 20 + eb] + b1cS[ej];
      float fv = gS[(32 + ej) * 20 + eb] + b1cS[32 + ej];
      float gv = gS[(64 + ej) * 20 + eb] + b1cS[64 + ej];
      float ov = gS[(96 + ej) * 20 + eb] + b1cS[96 + ej];
      float cn = sigm(fv) * cp_v + sigm(iv) * tanhf_(gv);
      float hv = sigm(ov) * tanhf_(cn);
      c_reg = cn;
      hS[eb * 520 + j0 + ej] = f2bf(hv);   // own chunk for next t's cell0
      if (t == T_ - 1) {
        out_h[(r0 + eb) * H_ + j0 + ej] = hv;
        out_c[(r0 + eb) * H_ + j0 + ej] = cn;
      }
      float p0 = __shfl(hv, lnm, 64);
      float p1 = __shfl(hv, lnm + 16, 64);
      float p2 = __shfl(hv, lnm + 32, 64);
      float p3 = __shfl(hv, lnm + 48, 64);
      if (ln < 16) {
        unsigned int tg = (unsigned int)(t + 1) << 16;
        unsigned long long q01 = ((unsigned long long)(tg | f2bf(p0))) |
                                 (((unsigned long long)(tg | f2bf(p1))) << 32);
        unsigned long long q23 = ((unsigned long long)(tg | f2bf(p2))) |
                                 (((unsigned long long)(tg | f2bf(p3))) << 32);
        unsigned long long* d = (unsigned long long*)(((t & 1) ? HB1 : HB0) +
                                                      (r0 + lnm) * 512 + j0 + wv * 4);
        __hip_atomic_store(d, q01, __ATOMIC_RELAXED, __HIP_MEMORY_SCOPE_AGENT);
        __hip_atomic_store(d + 1, q23, __ATOMIC_RELAXED, __HIP_MEMORY_SCOPE_AGENT);
      }
    }
  }
}

// ---------------- heads: cont_out + cls_out (f32) ----------------
__global__ __launch_bounds__(256) void k_heads(const float* __restrict__ h,
                                               const float* __restrict__ W_out,
                                               const float* __restrict__ b_out,
                                               const float* __restrict__ W_cls,
                                               const float* __restrict__ b_cls,
                                               float* __restrict__ out) {
  int o = blockIdx.x * 256 + threadIdx.x;
  if (o < B_ * NCONT_) {
    int b = o / NCONT_;
    int n = o - b * NCONT_;
    float acc = b_out[n];
    const float* hb = h + b * H_;
    for (int k = 0; k < H_; k += 4) {
      acc += hb[k] * W_out[k * NCONT_ + n] + hb[k + 1] * W_out[(k + 1) * NCONT_ + n] +
             hb[k + 2] * W_out[(k + 2) * NCONT_ + n] + hb[k + 3] * W_out[(k + 3) * NCONT_ + n];
    }
    out[o] = acc;
  } else {
    int oo = o - B_ * NCONT_;
    int b = oo >> 9;
    int r = oo & 511;
    int ci = r >> 4, cd = r & 15;
    float acc = b_cls[ci * 16 + cd];
    const float* hb = h + b * H_;
    const float* wc = W_cls + ci * 512 * 16 + cd;
    for (int k = 0; k < H_; k += 4) {
      acc += hb[k] * wc[k * 16] + hb[k + 1] * wc[(k + 1) * 16] + hb[k + 2] * wc[(k + 2) * 16] +
             hb[k + 3] * wc[(k + 3) * 16];
    }
    out[B_ * NCONT_ + oo] = acc;
  }
}

extern "C" void kernel_launch(void* const* d_in, const int* in_sizes, int n_in,
                              void* d_out, int out_size, void* d_ws, size_t ws_size,
                              hipStream_t stream) {
  const int* unscaled = (const int*)d_in[0];
  const float* scaled = (const float*)d_in[1];
  const float* emb = (const float*)d_in[2];
  const float* W_in = (const float*)d_in[3];
  const float* b_in = (const float*)d_in[4];
  const float* Wih0 = (const float*)d_in[5];
  const float* Whh0 = (const float*)d_in[6];
  const float* bih0 = (const float*)d_in[7];
  const float* bhh0 = (const float*)d_in[8];
  const float* Wih1 = (const float*)d_in[9];
  const float* Whh1 = (const float*)d_in[10];
  const float* bih1 = (const float*)d_in[11];
  const float* bhh1 = (const float*)d_in[12];
  const float* W_out = (const float*)d_in[13];
  const float* b_out = (const float*)d_in[14];
  const float* W_cls = (const float*)d_in[15];
  const float* b_cls = (const float*)d_in[16];

  // FEAT [0, 23068672) is dead after k_gemm1 -> Htag (1 MB, 4 slots x 128x512 u32)
  // overlays it, zero-init'ed after gemm1.
  const size_t o_feat = 0;                       // 23068672
  const size_t o_X = 23068672;                   // 33554432
  const size_t o_WinT = 56623104;                // 360448
  const size_t WS_NEED = 56983552;
  if (ws_size < WS_NEED) return;

  char* ws = (char*)d_ws;
  unsigned short* FEAT = (unsigned short*)(ws + o_feat);
  unsigned short* X = (unsigned short*)(ws + o_X);
  unsigned short* W_inT = (unsigned short*)(ws + o_WinT);
  unsigned int* Htag = (unsigned int*)(ws + o_feat);   // 1 MB overlay

  float* out = (float*)d_out;
  float* out_h = out + 77824;
  float* out_c = out + 143360;

  k_prep<<<704, 256, 0, stream>>>(W_in, W_inT);
  k_feat<<<8192, 256, 0, stream>>>(unscaled, scaled, emb, FEAT);
  k_gemm1<<<1024, 256, 0, stream>>>(FEAT, W_inT, b_in, X);
  k_initH<<<1024, 256, 0, stream>>>(Htag);
  k_lstm<<<128, 512, 0, stream>>>(Wih0, Whh0, bih0, bhh0, Wih1, Whh1, bih1, bhh1, X, Htag,
                                  out_h, out_c);
  k_heads<<<304, 256, 0, stream>>>(out_h, W_out, b_out, W_cls, b_cls, out);
}

// Round 5
// 2534.430 us; speedup vs baseline: 2.2024x; 2.2024x over previous
//
#include <hip/hip_runtime.h>
#include <stdint.h>

#define B_ 128
#define T_ 256
#define F_ 128
#define NCAT_ 32
#define CARD_ 16
#define E_ 8
#define H_ 512
#define INLEN_ 352
#define NCONT_ 96

typedef __bf16 bf16x8 __attribute__((ext_vector_type(8)));
typedef float f32x4 __attribute__((ext_vector_type(4)));
typedef unsigned short ushortx8 __attribute__((ext_vector_type(8)));

__device__ __forceinline__ unsigned short f2bf(float f) {
  unsigned int u = __float_as_uint(f);
  u += 0x7fffu + ((u >> 16) & 1u);   // RNE
  return (unsigned short)(u >> 16);
}
__device__ __forceinline__ float sigm(float x) { return 1.0f / (1.0f + __expf(-x)); }
__device__ __forceinline__ float tanhf_(float x) {
  float a = fabsf(x);
  float e = __expf(-2.0f * a);
  float t = (1.0f - e) / (1.0f + e);
  return x < 0.0f ? -t : t;
}

// ---------------- init: zero ONLY slot HB1 (the one pre-consumed slot; tag0 = h_{-1}=0) ----------------
__global__ void k_initH(unsigned int* Htag) {
  int id = blockIdx.x * 256 + threadIdx.x;   // 65536 words
  __hip_atomic_store(&Htag[196608 + id], 0u, __ATOMIC_RELAXED, __HIP_MEMORY_SCOPE_AGENT);
}

// ---------------- prep: W_in transposed -> bf16 (512 x 352) ----------------
__global__ void k_prep(const float* __restrict__ W_in, unsigned short* __restrict__ W_inT) {
  int id = blockIdx.x * 256 + threadIdx.x;
  if (id < 512 * INLEN_) {
    int n = id / INLEN_;
    int k = id - n * INLEN_;
    W_inT[id] = f2bf(W_in[k * 512 + n]);
  }
}

// ---------------- features: FEAT[t*128+b][352] bf16 ----------------
__global__ void k_feat(const int* __restrict__ unscaled, const float* __restrict__ scaled,
                       const float* __restrict__ emb, unsigned short* __restrict__ FEAT) {
  int row = blockIdx.x * 4 + (threadIdx.x >> 6);
  int t = row >> 7, b = row & 127;
  const int base = (b * T_ + t) * F_;
  for (int jj = (threadIdx.x & 63); jj < INLEN_; jj += 64) {
    int ci = jj / 11;
    int pos = jj - ci * 11;
    float v;
    if (pos < 8) {
      int cid = unscaled[base + 4 * ci];
      v = emb[(ci * CARD_ + cid) * E_ + pos];
    } else {
      v = scaled[base + 4 * ci + 1 + (pos - 8)];
    }
    FEAT[row * INLEN_ + jj] = f2bf(v);
  }
}

// ---------------- GEMM1: X = relu(FEAT @ W_in + b_in), bf16 out ----------------
__global__ __launch_bounds__(256) void k_gemm1(const unsigned short* __restrict__ FEAT,
                                               const unsigned short* __restrict__ W_inT,
                                               const float* __restrict__ b_in,
                                               unsigned short* __restrict__ X) {
  __shared__ __align__(16) unsigned short As[128 * 40];
  __shared__ __align__(16) unsigned short Bs[128 * 40];
  const int tid = threadIdx.x;
  const int Mtile = blockIdx.x >> 2;
  const int N0 = (blockIdx.x & 3) * 128;
  const int wv = tid >> 6, ln = tid & 63;
  const int lrow = ln & 15, lq = ln >> 4;
  f32x4 acc[2][8];
#pragma unroll
  for (int i = 0; i < 2; ++i)
#pragma unroll
    for (int j = 0; j < 8; ++j) acc[i][j] = (f32x4){0.f, 0.f, 0.f, 0.f};

  for (int kc = 0; kc < 11; ++kc) {
    int k0 = kc * 32;
#pragma unroll
    for (int i = 0; i < 2; ++i) {
      int c = i * 256 + tid;
      int row = c >> 2;
      int col = (c & 3) * 8;
      uint4 va = *(const uint4*)&FEAT[(Mtile * 128 + row) * INLEN_ + k0 + col];
      *(uint4*)&As[row * 40 + col] = va;
      uint4 vb = *(const uint4*)&W_inT[(N0 + row) * INLEN_ + k0 + col];
      *(uint4*)&Bs[row * 40 + col] = vb;
    }
    __syncthreads();
    bf16x8 af[2];
#pragma unroll
    for (int mt = 0; mt < 2; ++mt) {
      int r = wv * 32 + mt * 16 + lrow;
      af[mt] = __builtin_bit_cast(bf16x8, *(const ushortx8*)&As[r * 40 + lq * 8]);
    }
#pragma unroll
    for (int ntl = 0; ntl < 8; ++ntl) {
      bf16x8 bf = __builtin_bit_cast(bf16x8, *(const ushortx8*)&Bs[(ntl * 16 + lrow) * 40 + lq * 8]);
      acc[0][ntl] = __builtin_amdgcn_mfma_f32_16x16x32_bf16(af[0], bf, acc[0][ntl], 0, 0, 0);
      acc[1][ntl] = __builtin_amdgcn_mfma_f32_16x16x32_bf16(af[1], bf, acc[1][ntl], 0, 0, 0);
    }
    __syncthreads();
  }
#pragma unroll
  for (int mt = 0; mt < 2; ++mt)
#pragma unroll
    for (int ntl = 0; ntl < 8; ++ntl) {
      int n = N0 + ntl * 16 + lrow;
      float bias = b_in[n];
#pragma unroll
      for (int r = 0; r < 4; ++r) {
        int row = Mtile * 128 + wv * 32 + mt * 16 + lq * 4 + r;
        float v = acc[mt][ntl][r] + bias;
        v = v > 0.0f ? v : 0.0f;
        X[row * H_ + n] = f2bf(v);
      }
    }
}

// ---------------- persistent LSTM: 8 groups x 16 blocks, 512 thr ----------------
// Protocol (r5): tagged data words at agent scope; word = (tag16<<16)|bf16, tag=t+1.
//   Producer: stores tagged data coalesced and MOVES ON (no drain, no flag).
//   Consumer: wave 0 polls one SENTINEL word per peer block (16 lines),
//   s_sleep-throttled (r0's proven cheap-spin discipline); after confirm, one
//   bulk load + tag-validate with throttled rare retries (producer wave skew).
// Own chunk goes through LDS directly (never waits on own stores).
// Depth-2 ping-pong WAR-safe: overwrite at t+2 is data-dependent on validating
// peers' t+1 tags, which happens-after every peer's t-read completed.
// Tags <= 256 never wrap; zero-init of HB1 = tag0 = h_{-1}=0.
__device__ __forceinline__ void stageX(unsigned short* dst, const unsigned short* src, int tid) {
#pragma unroll
  for (int i = 0; i < 2; ++i) {
    int c = i * 512 + tid;
    int row = c >> 6;
    int col = (c & 63) * 8;
    uint4 v = *(const uint4*)&src[row * H_ + col];
    *(uint4*)&dst[row * 520 + col] = v;
  }
}

__device__ __forceinline__ void load8(unsigned long long vv[8], const unsigned long long* p) {
#pragma unroll
  for (int i = 0; i < 8; ++i)
    vv[i] = __hip_atomic_load(p + i, __ATOMIC_RELAXED, __HIP_MEMORY_SCOPE_AGENT);
}
__device__ __forceinline__ bool check8(const unsigned long long vv[8], unsigned int exp) {
  unsigned int d = 0;
#pragma unroll
  for (int i = 0; i < 8; ++i) {
    d |= (((unsigned int)(vv[i] >> 16)) & 0xFFFFu) ^ exp;
    d |= ((unsigned int)(vv[i] >> 48)) ^ exp;
  }
  return d == 0;
}
__device__ __forceinline__ void strip8(const unsigned long long vv[8], unsigned short* hS,
                                       int base) {
#pragma unroll
  for (int i = 0; i < 8; ++i) {
    unsigned int w = ((unsigned int)vv[i] & 0xFFFFu) | (((unsigned int)(vv[i] >> 32)) << 16);
    *(unsigned int*)&hS[base + 2 * i] = w;
  }
}

// wave-0-only: poll peer sentinels (1 tagged word per peer block), sleep-throttled
__device__ __forceinline__ void sentinelPoll(const unsigned int* slot, int r0, int bc, int ln,
                                             unsigned int exp, int& guard) {
  const unsigned int* sp = slot + r0 * 512 + 32 * (ln & 15);
  const bool mine = (ln & 15) == bc;
  for (;;) {
    unsigned int v = mine ? (exp << 16)
                          : __hip_atomic_load(sp, __ATOMIC_RELAXED, __HIP_MEMORY_SCOPE_AGENT);
    if (__all((int)((v >> 16) >= exp))) break;
    if (++guard > 4000000) break;   // bail -> wrong answer instead of hang
    __builtin_amdgcn_s_sleep(1);
  }
}

// all threads: bulk load + tag-validate (throttled retry), strip to LDS
__device__ __forceinline__ void consumeT(const unsigned long long* src, unsigned int exp,
                                         bool skip, unsigned short* hS, int ldsOff, int& guard) {
  unsigned long long vv[8];
  bool ok = skip;
  if (!skip) {
    load8(vv, src);
    ok = check8(vv, exp);
  }
  while (!__all((int)ok)) {
    __builtin_amdgcn_s_sleep(1);
    if (!ok) {
      load8(vv, src);
      ok = check8(vv, exp);
    }
    if (++guard > 4000000) break;
  }
  if (!skip) strip8(vv, hS, ldsOff);
}

__global__ __launch_bounds__(512, 2) void k_lstm(
    const float* __restrict__ Wih0, const float* __restrict__ Whh0,
    const float* __restrict__ bih0, const float* __restrict__ bhh0,
    const float* __restrict__ Wih1, const float* __restrict__ Whh1,
    const float* __restrict__ bih1, const float* __restrict__ bhh1,
    const unsigned short* __restrict__ X, unsigned int* __restrict__ Htag,
    float* __restrict__ out_h, float* __restrict__ out_c) {
  __shared__ __align__(16) unsigned short hS[16 * 520];
  __shared__ __align__(16) unsigned short xS[16 * 520];
  __shared__ __align__(16) float gS[128 * 20];
  __shared__ float b0cS[128], b1cS[128];

  const int tid = threadIdx.x;
  const int group = blockIdx.x & 7;    // XCD-packed (r2: halves FETCH via X dedup in L2)
  const int bc = blockIdx.x >> 3;      // 0..15 : h-cols j0..j0+31
  const int j0 = bc * 32;
  const int r0 = group * 16;
  const int wv = tid >> 6, ln = tid & 63;
  const int lrow = ln & 15, lq = ln >> 4;
  const int n_local = wv * 16 + lrow;                              // 0..127 gate-col in block
  const int gcol = ((n_local >> 5) << 9) + j0 + (n_local & 31);    // gate*512 + hcol

  // one-time: weight B-fragments in registers (bf16), combined biases in LDS
  bf16x8 Bf0[32], Bf1[16];
  {
    const float* s0 = Wih0 + gcol * H_;
    const float* s1 = Whh0 + gcol * H_;
#pragma unroll
    for (int ks = 0; ks < 32; ++ks) {
      int k = (ks & 15) * 32 + lq * 8;
      const float* s = (ks < 16) ? (s0 + k) : (s1 + k);
      ushortx8 u;
#pragma unroll
      for (int j = 0; j < 8; ++j) u[j] = f2bf(s[j]);
      Bf0[ks] = __builtin_bit_cast(bf16x8, u);
    }
    const float* sa = Wih1 + gcol * H_;
    const float* sb = Whh1 + gcol * H_;
#pragma unroll
    for (int ks = 0; ks < 16; ++ks) {
      int k = ks * 32 + lq * 8;
      ushortx8 u;
#pragma unroll
      for (int j = 0; j < 8; ++j) u[j] = f2bf(sa[k + j] + sb[k + j]);
      Bf1[ks] = __builtin_bit_cast(bf16x8, u);
    }
  }
  if (tid < 128) {
    int g2 = ((tid >> 5) << 9) + j0 + (tid & 31);
    b0cS[tid] = bih0[g2] + bhh0[g2];
    b1cS[tid] = bih1[g2] + bhh1[g2];
  }

  unsigned int* const HA0 = Htag;             // cell0 h, slot 0
  unsigned int* const HA1 = Htag + 65536;     // cell0 h, slot 1
  unsigned int* const HB0 = Htag + 131072;    // cell1 h, slot 0
  unsigned int* const HB1 = Htag + 196608;    // cell1 h, slot 1 (zero-init'ed)

  const int eb = tid & 15, ej = tid >> 4;   // elementwise ownership: row eb, h-col j0+ej
  const int fragOff = lrow * 520 + lq * 8;
  const int lnm = ln & 15;
  // consume mapping: each thread owns one 64B line (8 u64 = 16 tagged cols)
  const int crow = tid >> 5;                        // 0..15
  const int cb = tid & 31;                          // 16-col block
  const bool skip = ((cb >> 1) == bc);              // own chunk -> comes via LDS
  const int srcOff = (r0 + crow) * 256 + cb * 8;    // u64 units
  const int ldsOff = crow * 520 + cb * 16;          // short units
  float c_reg = 0.0f, cp_v = 0.0f;
  int guard = 0;

  stageX(xS, X + (0 * B_ + r0) * H_, tid);   // preload X_0
  __syncthreads();

#pragma unroll 1
  for (int t = 0; t < T_; ++t) {
    // ======== cell 0 ========
    unsigned int* const slot0 = ((t + 1) & 1) ? HB1 : HB0;
    f32x4 acc = (f32x4){0.f, 0.f, 0.f, 0.f};
#pragma unroll
    for (int ks = 0; ks < 16; ++ks) {   // x-part: independent of peers -> before wait
      bf16x8 a = __builtin_bit_cast(bf16x8, *(const ushortx8*)&xS[fragOff + ks * 32]);
      acc = __builtin_amdgcn_mfma_f32_16x16x32_bf16(a, Bf0[ks], acc, 0, 0, 0);
    }
    if (wv == 0) sentinelPoll(slot0, r0, bc, ln, (unsigned int)t, guard);
    __builtin_amdgcn_s_barrier();   // release all waves once wave0 confirmed
    consumeT((const unsigned long long*)slot0 + srcOff, (unsigned int)t, skip, hS, ldsOff, guard);
    __syncthreads();
#pragma unroll
    for (int ks = 0; ks < 16; ++ks) {
      bf16x8 a = __builtin_bit_cast(bf16x8, *(const ushortx8*)&hS[fragOff + ks * 32]);
      acc = __builtin_amdgcn_mfma_f32_16x16x32_bf16(a, Bf0[16 + ks], acc, 0, 0, 0);
    }
    *(f32x4*)&gS[n_local * 20 + lq * 4] = acc;
    __syncthreads();
    {
      float iv = gS[(ej) * 20 + eb] + b0cS[ej];
      float fv = gS[(32 + ej) * 20 + eb] + b0cS[32 + ej];
      float gv = gS[(64 + ej) * 20 + eb] + b0cS[64 + ej];
      float ov = gS[(96 + ej) * 20 + eb] + b0cS[96 + ej];
      cp_v = sigm(fv) * c_reg + sigm(iv) * tanhf_(gv);
      float hv = sigm(ov) * tanhf_(cp_v);
      hS[eb * 520 + j0 + ej] = f2bf(hv);   // own chunk straight to LDS
      // coalesced tagged publish: lanes 0..15 store 2 u64 (16B contiguous); no drain, no flag
      float p0 = __shfl(hv, lnm, 64);
      float p1 = __shfl(hv, lnm + 16, 64);
      float p2 = __shfl(hv, lnm + 32, 64);
      float p3 = __shfl(hv, lnm + 48, 64);
      if (ln < 16) {
        unsigned int tg = (unsigned int)(t + 1) << 16;
        unsigned long long q01 = ((unsigned long long)(tg | f2bf(p0))) |
                                 (((unsigned long long)(tg | f2bf(p1))) << 32);
        unsigned long long q23 = ((unsigned long long)(tg | f2bf(p2))) |
                                 (((unsigned long long)(tg | f2bf(p3))) << 32);
        unsigned long long* d = (unsigned long long*)(((t & 1) ? HA1 : HA0) +
                                                      (r0 + lnm) * 512 + j0 + wv * 4);
        __hip_atomic_store(d, q01, __ATOMIC_RELAXED, __HIP_MEMORY_SCOPE_AGENT);
        __hip_atomic_store(d + 1, q23, __ATOMIC_RELAXED, __HIP_MEMORY_SCOPE_AGENT);
      }
    }

    // ======== cell 1 ========
    unsigned int* const slot1 = (t & 1) ? HA1 : HA0;
    if (t + 1 < T_) stageX(xS, X + ((t + 1) * B_ + r0) * H_, tid);   // prefetch next X
    if (wv == 0) sentinelPoll(slot1, r0, bc, ln, (unsigned int)(t + 1), guard);
    __builtin_amdgcn_s_barrier();
    consumeT((const unsigned long long*)slot1 + srcOff, (unsigned int)(t + 1), skip, hS, ldsOff,
             guard);
    __syncthreads();
    acc = (f32x4){0.f, 0.f, 0.f, 0.f};
#pragma unroll
    for (int ks = 0; ks < 16; ++ks) {
      bf16x8 a = __builtin_bit_cast(bf16x8, *(const ushortx8*)&hS[fragOff + ks * 32]);
      acc = __builtin_amdgcn_mfma_f32_16x16x32_bf16(a, Bf1[ks], acc, 0, 0, 0);
    }
    *(f32x4*)&gS[n_local * 20 + lq * 4] = acc;
    __syncthreads();
    {
      float iv = gS[(ej) * 20 + eb] + b1cS[ej];
      float fv = gS[(32 + ej) * 20 + eb] + b1cS[32 + ej];
      float gv = gS[(64 + ej) * 20 + eb] + b1cS[64 + ej];
      float ov = gS[(96 + ej) * 20 + eb] + b1cS[96 + ej];
      float cn = sigm(fv) * cp_v + sigm(iv) * tanhf_(gv);
      float hv = sigm(ov) * tanhf_(cn);
      c_reg = cn;
      hS[eb * 520 + j0 + ej] = f2bf(hv);   // own chunk for next t's cell0
      if (t == T_ - 1) {
        out_h[(r0 + eb) * H_ + j0 + ej] = hv;
        out_c[(r0 + eb) * H_ + j0 + ej] = cn;
      }
      float p0 = __shfl(hv, lnm, 64);
      float p1 = __shfl(hv, lnm + 16, 64);
      float p2 = __shfl(hv, lnm + 32, 64);
      float p3 = __shfl(hv, lnm + 48, 64);
      if (ln < 16) {
        unsigned int tg = (unsigned int)(t + 1) << 16;
        unsigned long long q01 = ((unsigned long long)(tg | f2bf(p0))) |
                                 (((unsigned long long)(tg | f2bf(p1))) << 32);
        unsigned long long q23 = ((unsigned long long)(tg | f2bf(p2))) |
                                 (((unsigned long long)(tg | f2bf(p3))) << 32);
        unsigned long long* d = (unsigned long long*)(((t & 1) ? HB1 : HB0) +
                                                      (r0 + lnm) * 512 + j0 + wv * 4);
        __hip_atomic_store(d, q01, __ATOMIC_RELAXED, __HIP_MEMORY_SCOPE_AGENT);
        __hip_atomic_store(d + 1, q23, __ATOMIC_RELAXED, __HIP_MEMORY_SCOPE_AGENT);
      }
    }
  }
}

// ---------------- heads: cont_out + cls_out (f32) ----------------
__global__ __launch_bounds__(256) void k_heads(const float* __restrict__ h,
                                               const float* __restrict__ W_out,
                                               const float* __restrict__ b_out,
                                               const float* __restrict__ W_cls,
                                               const float* __restrict__ b_cls,
                                               float* __restrict__ out) {
  int o = blockIdx.x * 256 + threadIdx.x;
  if (o < B_ * NCONT_) {
    int b = o / NCONT_;
    int n = o - b * NCONT_;
    float acc = b_out[n];
    const float* hb = h + b * H_;
    for (int k = 0; k < H_; k += 4) {
      acc += hb[k] * W_out[k * NCONT_ + n] + hb[k + 1] * W_out[(k + 1) * NCONT_ + n] +
             hb[k + 2] * W_out[(k + 2) * NCONT_ + n] + hb[k + 3] * W_out[(k + 3) * NCONT_ + n];
    }
    out[o] = acc;
  } else {
    int oo = o - B_ * NCONT_;
    int b = oo >> 9;
    int r = oo & 511;
    int ci = r >> 4, cd = r & 15;
    float acc = b_cls[ci * 16 + cd];
    const float* hb = h + b * H_;
    const float* wc = W_cls + ci * 512 * 16 + cd;
    for (int k = 0; k < H_; k += 4) {
      acc += hb[k] * wc[k * 16] + hb[k + 1] * wc[(k + 1) * 16] + hb[k + 2] * wc[(k + 2) * 16] +
             hb[k + 3] * wc[(k + 3) * 16];
    }
    out[B_ * NCONT_ + oo] = acc;
  }
}

extern "C" void kernel_launch(void* const* d_in, const int* in_sizes, int n_in,
                              void* d_out, int out_size, void* d_ws, size_t ws_size,
                              hipStream_t stream) {
  const int* unscaled = (const int*)d_in[0];
  const float* scaled = (const float*)d_in[1];
  const float* emb = (const float*)d_in[2];
  const float* W_in = (const float*)d_in[3];
  const float* b_in = (const float*)d_in[4];
  const float* Wih0 = (const float*)d_in[5];
  const float* Whh0 = (const float*)d_in[6];
  const float* bih0 = (const float*)d_in[7];
  const float* bhh0 = (const float*)d_in[8];
  const float* Wih1 = (const float*)d_in[9];
  const float* Whh1 = (const float*)d_in[10];
  const float* bih1 = (const float*)d_in[11];
  const float* bhh1 = (const float*)d_in[12];
  const float* W_out = (const float*)d_in[13];
  const float* b_out = (const float*)d_in[14];
  const float* W_cls = (const float*)d_in[15];
  const float* b_cls = (const float*)d_in[16];

  // FEAT [0, 23068672) is dead after k_gemm1 -> Htag (1 MB, 4 slots x 128x512 u32)
  // overlays it; only slot HB1 needs zero-init (after gemm1).
  const size_t o_feat = 0;                       // 23068672
  const size_t o_X = 23068672;                   // 33554432
  const size_t o_WinT = 56623104;                // 360448
  const size_t WS_NEED = 56983552;
  if (ws_size < WS_NEED) return;

  char* ws = (char*)d_ws;
  unsigned short* FEAT = (unsigned short*)(ws + o_feat);
  unsigned short* X = (unsigned short*)(ws + o_X);
  unsigned short* W_inT = (unsigned short*)(ws + o_WinT);
  unsigned int* Htag = (unsigned int*)(ws + o_feat);   // 1 MB overlay

  float* out = (float*)d_out;
  float* out_h = out + 77824;
  float* out_c = out + 143360;

  k_prep<<<704, 256, 0, stream>>>(W_in, W_inT);
  k_feat<<<8192, 256, 0, stream>>>(unscaled, scaled, emb, FEAT);
  k_gemm1<<<1024, 256, 0, stream>>>(FEAT, W_inT, b_in, X);
  k_initH<<<256, 256, 0, stream>>>(Htag);
  k_lstm<<<128, 512, 0, stream>>>(Wih0, Whh0, bih0, bhh0, Wih1, Whh1, bih1, bhh1, X, Htag,
                                  out_h, out_c);
  k_heads<<<304, 256, 0, stream>>>(out_h, W_out, b_out, W_cls, b_cls, out);
}

// Round 7
// 1704.349 us; speedup vs baseline: 3.2750x; 1.4870x over previous
//
#include <hip/hip_runtime.h>
#include <stdint.h>

#define B_ 128
#define T_ 256
#define F_ 128
#define NCAT_ 32
#define CARD_ 16
#define E_ 8
#define H_ 512
#define INLEN_ 352
#define NCONT_ 96

typedef __bf16 bf16x8 __attribute__((ext_vector_type(8)));
typedef float f32x4 __attribute__((ext_vector_type(4)));
typedef unsigned short ushortx8 __attribute__((ext_vector_type(8)));
typedef unsigned int u32x4 __attribute__((ext_vector_type(4)));   // asm-friendly 128-bit

__device__ __forceinline__ unsigned short f2bf(float f) {
  unsigned int u = __float_as_uint(f);
  u += 0x7fffu + ((u >> 16) & 1u);   // RNE
  return (unsigned short)(u >> 16);
}
__device__ __forceinline__ float sigm(float x) { return 1.0f / (1.0f + __expf(-x)); }
__device__ __forceinline__ float tanhf_(float x) {
  float a = fabsf(x);
  float e = __expf(-2.0f * a);
  float t = (1.0f - e) / (1.0f + e);
  return x < 0.0f ? -t : t;
}

// ---------------- init: zero h buffer B and flags ----------------
__global__ void k_init(unsigned int* bufB_u32, unsigned int* flags) {
  if (blockIdx.x < 128) {
    __hip_atomic_store(&bufB_u32[blockIdx.x * 256 + threadIdx.x], 0u, __ATOMIC_RELAXED,
                       __HIP_MEMORY_SCOPE_AGENT);
  } else {
    __hip_atomic_store(&flags[threadIdx.x], 0u, __ATOMIC_RELAXED, __HIP_MEMORY_SCOPE_AGENT);
  }
}

// ---------------- prep: W_in transposed -> bf16 (512 x 352) ----------------
__global__ void k_prep(const float* __restrict__ W_in, unsigned short* __restrict__ W_inT) {
  int id = blockIdx.x * 256 + threadIdx.x;
  if (id < 512 * INLEN_) {
    int n = id / INLEN_;
    int k = id - n * INLEN_;
    W_inT[id] = f2bf(W_in[k * 512 + n]);
  }
}

// ---------------- features: FEAT[t*128+b][352] bf16 ----------------
__global__ void k_feat(const int* __restrict__ unscaled, const float* __restrict__ scaled,
                       const float* __restrict__ emb, unsigned short* __restrict__ FEAT) {
  int row = blockIdx.x * 4 + (threadIdx.x >> 6);
  int t = row >> 7, b = row & 127;
  const int base = (b * T_ + t) * F_;
  for (int jj = (threadIdx.x & 63); jj < INLEN_; jj += 64) {
    int ci = jj / 11;
    int pos = jj - ci * 11;
    float v;
    if (pos < 8) {
      int cid = unscaled[base + 4 * ci];
      v = emb[(ci * CARD_ + cid) * E_ + pos];
    } else {
      v = scaled[base + 4 * ci + 1 + (pos - 8)];
    }
    FEAT[row * INLEN_ + jj] = f2bf(v);
  }
}

// ---------------- GEMM1: X = relu(FEAT @ W_in + b_in), bf16 out ----------------
__global__ __launch_bounds__(256) void k_gemm1(const unsigned short* __restrict__ FEAT,
                                               const unsigned short* __restrict__ W_inT,
                                               const float* __restrict__ b_in,
                                               unsigned short* __restrict__ X) {
  __shared__ __align__(16) unsigned short As[128 * 40];
  __shared__ __align__(16) unsigned short Bs[128 * 40];
  const int tid = threadIdx.x;
  const int Mtile = blockIdx.x >> 2;
  const int N0 = (blockIdx.x & 3) * 128;
  const int wv = tid >> 6, ln = tid & 63;
  const int lrow = ln & 15, lq = ln >> 4;
  f32x4 acc[2][8];
#pragma unroll
  for (int i = 0; i < 2; ++i)
#pragma unroll
    for (int j = 0; j < 8; ++j) acc[i][j] = (f32x4){0.f, 0.f, 0.f, 0.f};

  for (int kc = 0; kc < 11; ++kc) {
    int k0 = kc * 32;
#pragma unroll
    for (int i = 0; i < 2; ++i) {
      int c = i * 256 + tid;
      int row = c >> 2;
      int col = (c & 3) * 8;
      uint4 va = *(const uint4*)&FEAT[(Mtile * 128 + row) * INLEN_ + k0 + col];
      *(uint4*)&As[row * 40 + col] = va;
      uint4 vb = *(const uint4*)&W_inT[(N0 + row) * INLEN_ + k0 + col];
      *(uint4*)&Bs[row * 40 + col] = vb;
    }
    __syncthreads();
    bf16x8 af[2];
#pragma unroll
    for (int mt = 0; mt < 2; ++mt) {
      int r = wv * 32 + mt * 16 + lrow;
      af[mt] = __builtin_bit_cast(bf16x8, *(const ushortx8*)&As[r * 40 + lq * 8]);
    }
#pragma unroll
    for (int ntl = 0; ntl < 8; ++ntl) {
      bf16x8 bf = __builtin_bit_cast(bf16x8, *(const ushortx8*)&Bs[(ntl * 16 + lrow) * 40 + lq * 8]);
      acc[0][ntl] = __builtin_amdgcn_mfma_f32_16x16x32_bf16(af[0], bf, acc[0][ntl], 0, 0, 0);
      acc[1][ntl] = __builtin_amdgcn_mfma_f32_16x16x32_bf16(af[1], bf, acc[1][ntl], 0, 0, 0);
    }
    __syncthreads();
  }
#pragma unroll
  for (int mt = 0; mt < 2; ++mt)
#pragma unroll
    for (int ntl = 0; ntl < 8; ++ntl) {
      int n = N0 + ntl * 16 + lrow;
      float bias = b_in[n];
#pragma unroll
      for (int r = 0; r < 4; ++r) {
        int row = Mtile * 128 + wv * 32 + mt * 16 + lq * 4 + r;
        float v = acc[mt][ntl][r] + bias;
        v = v > 0.0f ? v : 0.0f;
        X[row * H_ + n] = f2bf(v);
      }
    }
}

// ---------------- persistent LSTM: 8 groups x 16 blocks, 512 thr ----------------
// Protocol = r0 (flags + drain + sleep-throttled poll; WAR-safe via the flag
// dependence chain). Memory-system fixes vs r0:
//  - publish: wave0 stores the block's 16 rows x 64B as full-line dwordx4 (4
//    lanes/line, one instruction) -> HW write-combining, no partial-line RMW.
//  - consume: full-line dwordx4 sc0 sc1 loads (bypass to coherence point).
//  - wave0-only flag poll, s_barrier release (8x less poll traffic).
__device__ __forceinline__ void stageX(unsigned short* dst, const unsigned short* src, int tid) {
#pragma unroll
  for (int i = 0; i < 2; ++i) {
    int c = i * 512 + tid;
    int row = c >> 6;
    int col = (c & 63) * 8;
    uint4 v = *(const uint4*)&src[row * H_ + col];
    *(uint4*)&dst[row * 520 + col] = v;
  }
}

__device__ __forceinline__ void stageH(unsigned short* dst, const unsigned short* src, int tid) {
  const int c0 = tid, c1 = 512 + tid;
  const unsigned short* p0 = src + (c0 >> 6) * H_ + (c0 & 63) * 8;
  const unsigned short* p1 = src + (c1 >> 6) * H_ + (c1 & 63) * 8;
  u32x4 v0, v1;
  asm volatile("global_load_dwordx4 %0, %1, off sc0 sc1" : "=v"(v0) : "v"(p0));
  asm volatile("global_load_dwordx4 %0, %1, off sc0 sc1" : "=v"(v1) : "v"(p1));
  asm volatile("s_waitcnt vmcnt(0)" ::: "memory");
  *(u32x4*)&dst[(c0 >> 6) * 520 + (c0 & 63) * 8] = v0;
  *(u32x4*)&dst[(c1 >> 6) * 520 + (c1 & 63) * 8] = v1;
}

// wave0: publish own 16x64B chunk from hS as full lines (4 lanes per 64B line)
__device__ __forceinline__ void publishRows(unsigned short* buf, const unsigned short* hS,
                                            int r0, int j0, int ln) {
  const int r = ln >> 2, q = ln & 3;
  u32x4 v = *(const u32x4*)&hS[r * 520 + j0 + q * 8];
  unsigned short* d = buf + (r0 + r) * H_ + j0 + q * 8;
  asm volatile("global_store_dwordx4 %0, %1, off sc0 sc1" ::"v"(d), "v"(v) : "memory");
}

__device__ __forceinline__ void pollwait(const unsigned int* fp, unsigned int expect, int& guard) {
  for (;;) {
    unsigned int v = __hip_atomic_load(fp, __ATOMIC_RELAXED, __HIP_MEMORY_SCOPE_AGENT);
    if (__all((int)(v >= expect))) break;
    if (++guard > 4000000) break;   // deadlock bail -> wrong answer instead of hang
    __builtin_amdgcn_s_sleep(1);
  }
}

__global__ __launch_bounds__(512, 2) void k_lstm(
    const float* __restrict__ Wih0, const float* __restrict__ Whh0,
    const float* __restrict__ bih0, const float* __restrict__ bhh0,
    const float* __restrict__ Wih1, const float* __restrict__ Whh1,
    const float* __restrict__ bih1, const float* __restrict__ bhh1,
    const unsigned short* __restrict__ X, unsigned short* __restrict__ bufA,
    unsigned short* __restrict__ bufB, unsigned int* flagsA, unsigned int* flagsB,
    float* __restrict__ out_h, float* __restrict__ out_c) {
  __shared__ __align__(16) unsigned short hS[16 * 520];
  __shared__ __align__(16) unsigned short xS[16 * 520];
  __shared__ __align__(16) float gS[128 * 20];
  __shared__ float b0cS[128], b1cS[128];

  const int tid = threadIdx.x;
  const int group = blockIdx.x & 7;    // XCD-packed: group's 16 blocks share an XCD (r2: FETCH/2)
  const int bc = blockIdx.x >> 3;      // 0..15 : h-cols j0..j0+31
  const int j0 = bc * 32;
  const int r0 = group * 16;
  const int wv = tid >> 6, ln = tid & 63;
  const int lrow = ln & 15, lq = ln >> 4;
  const int n_local = wv * 16 + lrow;                              // 0..127 gate-col in block
  const int gcol = ((n_local >> 5) << 9) + j0 + (n_local & 31);    // gate*512 + hcol

  // one-time: weight B-fragments in registers (bf16), combined biases in LDS
  bf16x8 Bf0[32], Bf1[16];
  {
    const float* s0 = Wih0 + gcol * H_;
    const float* s1 = Whh0 + gcol * H_;
#pragma unroll
    for (int ks = 0; ks < 32; ++ks) {
      int k = (ks & 15) * 32 + lq * 8;
      const float* s = (ks < 16) ? (s0 + k) : (s1 + k);
      ushortx8 u;
#pragma unroll
      for (int j = 0; j < 8; ++j) u[j] = f2bf(s[j]);
      Bf0[ks] = __builtin_bit_cast(bf16x8, u);
    }
    const float* sa = Wih1 + gcol * H_;
    const float* sb = Whh1 + gcol * H_;
#pragma unroll
    for (int ks = 0; ks < 16; ++ks) {
      int k = ks * 32 + lq * 8;
      ushortx8 u;
#pragma unroll
      for (int j = 0; j < 8; ++j) u[j] = f2bf(sa[k + j] + sb[k + j]);
      Bf1[ks] = __builtin_bit_cast(bf16x8, u);
    }
  }
  if (tid < 128) {
    int g2 = ((tid >> 5) << 9) + j0 + (tid & 31);
    b0cS[tid] = bih0[g2] + bhh0[g2];
    b1cS[tid] = bih1[g2] + bhh1[g2];
  }

  unsigned int* fA = flagsA + group * 16;
  unsigned int* fB = flagsB + group * 16;
  unsigned int* myA = fA + bc;
  unsigned int* myB = fB + bc;
  const unsigned int* pollA = fA + (ln & 15);
  const unsigned int* pollB = fB + (ln & 15);

  const int eb = tid & 15, ej = tid >> 4;   // elementwise ownership: row eb, h-col j0+ej
  const int fragOff = lrow * 520 + lq * 8;
  float c_reg = 0.0f, cp_v = 0.0f;
  int guard = 0;

  stageX(xS, X + (0 * B_ + r0) * H_, tid);   // preload X_0
  __syncthreads();

#pragma unroll 1
  for (int t = 0; t < T_; ++t) {
    // ======== cell 0 ========
    f32x4 acc0 = (f32x4){0.f, 0.f, 0.f, 0.f};
    f32x4 acc1 = (f32x4){0.f, 0.f, 0.f, 0.f};
#pragma unroll
    for (int ks = 0; ks < 16; ks += 2) {   // x-part: independent of peers -> before poll
      bf16x8 a0 = __builtin_bit_cast(bf16x8, *(const ushortx8*)&xS[fragOff + ks * 32]);
      acc0 = __builtin_amdgcn_mfma_f32_16x16x32_bf16(a0, Bf0[ks], acc0, 0, 0, 0);
      bf16x8 a1 = __builtin_bit_cast(bf16x8, *(const ushortx8*)&xS[fragOff + (ks + 1) * 32]);
      acc1 = __builtin_amdgcn_mfma_f32_16x16x32_bf16(a1, Bf0[ks + 1], acc1, 0, 0, 0);
    }
    if (wv == 0) pollwait(pollB, (unsigned int)t, guard);   // h1_{t-1} ready (t=0 trivial)
    __builtin_amdgcn_s_barrier();
    stageH(hS, bufB + r0 * H_, tid);
    __syncthreads();
#pragma unroll
    for (int ks = 0; ks < 16; ks += 2) {
      bf16x8 a0 = __builtin_bit_cast(bf16x8, *(const ushortx8*)&hS[fragOff + ks * 32]);
      acc0 = __builtin_amdgcn_mfma_f32_16x16x32_bf16(a0, Bf0[16 + ks], acc0, 0, 0, 0);
      bf16x8 a1 = __builtin_bit_cast(bf16x8, *(const ushortx8*)&hS[fragOff + (ks + 1) * 32]);
      acc1 = __builtin_amdgcn_mfma_f32_16x16x32_bf16(a1, Bf0[16 + ks + 1], acc1, 0, 0, 0);
    }
    *(f32x4*)&gS[n_local * 20 + lq * 4] = acc0 + acc1;
    __syncthreads();
    {
      float iv = gS[(ej) * 20 + eb] + b0cS[ej];
      float fv = gS[(32 + ej) * 20 + eb] + b0cS[32 + ej];
      float gv = gS[(64 + ej) * 20 + eb] + b0cS[64 + ej];
      float ov = gS[(96 + ej) * 20 + eb] + b0cS[96 + ej];
      cp_v = sigm(fv) * c_reg + sigm(iv) * tanhf_(gv);
      float hv = sigm(ov) * tanhf_(cp_v);
      hS[eb * 520 + j0 + ej] = f2bf(hv);   // marshal own h through LDS
    }
    __syncthreads();   // hS own-chunk complete for wave0 marshal
    if (wv == 0) {
      publishRows(bufA, hS, r0, j0, ln);                     // full-line stores, no RMW
      asm volatile("s_waitcnt vmcnt(0)" ::: "memory");       // data acked at coherence point
      if (ln == 0) __hip_atomic_store(myA, (unsigned int)(t + 1), __ATOMIC_RELAXED,
                                      __HIP_MEMORY_SCOPE_AGENT);
    }

    // ======== cell 1 ========
    if (t + 1 < T_) stageX(xS, X + ((t + 1) * B_ + r0) * H_, tid);   // prefetch next X
    if (wv == 0) pollwait(pollA, (unsigned int)(t + 1), guard);
    __builtin_amdgcn_s_barrier();
    stageH(hS, bufA + r0 * H_, tid);
    __syncthreads();
    acc0 = (f32x4){0.f, 0.f, 0.f, 0.f};
    acc1 = (f32x4){0.f, 0.f, 0.f, 0.f};
#pragma unroll
    for (int ks = 0; ks < 16; ks += 2) {
      bf16x8 a0 = __builtin_bit_cast(bf16x8, *(const ushortx8*)&hS[fragOff + ks * 32]);
      acc0 = __builtin_amdgcn_mfma_f32_16x16x32_bf16(a0, Bf1[ks], acc0, 0, 0, 0);
      bf16x8 a1 = __builtin_bit_cast(bf16x8, *(const ushortx8*)&hS[fragOff + (ks + 1) * 32]);
      acc1 = __builtin_amdgcn_mfma_f32_16x16x32_bf16(a1, Bf1[ks + 1], acc1, 0, 0, 0);
    }
    *(f32x4*)&gS[n_local * 20 + lq * 4] = acc0 + acc1;
    __syncthreads();
    {
      float iv = gS[(ej) * 20 + eb] + b1cS[ej];
      float fv = gS[(32 + ej) * 20 + eb] + b1cS[32 + ej];
      float gv = gS[(64 + ej) * 20 + eb] + b1cS[64 + ej];
      float ov = gS[(96 + ej) * 20 + eb] + b1cS[96 + ej];
      float cn = sigm(fv) * cp_v + sigm(iv) * tanhf_(gv);
      float hv = sigm(ov) * tanhf_(cn);
      c_reg = cn;
      hS[eb * 520 + j0 + ej] = f2bf(hv);
      if (t == T_ - 1) {
        out_h[(r0 + eb) * H_ + j0 + ej] = hv;
        out_c[(r0 + eb) * H_ + j0 + ej] = cn;
      }
    }
    __syncthreads();
    if (wv == 0) {
      publishRows(bufB, hS, r0, j0, ln);
      asm volatile("s_waitcnt vmcnt(0)" ::: "memory");
      if (ln == 0) __hip_atomic_store(myB, (unsigned int)(t + 1), __ATOMIC_RELAXED,
                                      __HIP_MEMORY_SCOPE_AGENT);
    }
  }
}

// ---------------- heads: cont_out + cls_out (f32) ----------------
__global__ __launch_bounds__(256) void k_heads(const float* __restrict__ h,
                                               const float* __restrict__ W_out,
                                               const float* __restrict__ b_out,
                                               const float* __restrict__ W_cls,
                                               const float* __restrict__ b_cls,
                                               float* __restrict__ out) {
  int o = blockIdx.x * 256 + threadIdx.x;
  if (o < B_ * NCONT_) {
    int b = o / NCONT_;
    int n = o - b * NCONT_;
    float acc = b_out[n];
    const float* hb = h + b * H_;
    for (int k = 0; k < H_; k += 4) {
      acc += hb[k] * W_out[k * NCONT_ + n] + hb[k + 1] * W_out[(k + 1) * NCONT_ + n] +
             hb[k + 2] * W_out[(k + 2) * NCONT_ + n] + hb[k + 3] * W_out[(k + 3) * NCONT_ + n];
    }
    out[o] = acc;
  } else {
    int oo = o - B_ * NCONT_;
    int b = oo >> 9;
    int r = oo & 511;
    int ci = r >> 4, cd = r & 15;
    float acc = b_cls[ci * 16 + cd];
    const float* hb = h + b * H_;
    const float* wc = W_cls + ci * 512 * 16 + cd;
    for (int k = 0; k < H_; k += 4) {
      acc += hb[k] * wc[k * 16] + hb[k + 1] * wc[(k + 1) * 16] + hb[k + 2] * wc[(k + 2) * 16] +
             hb[k + 3] * wc[(k + 3) * 16];
    }
    out[B_ * NCONT_ + oo] = acc;
  }
}

extern "C" void kernel_launch(void* const* d_in, const int* in_sizes, int n_in,
                              void* d_out, int out_size, void* d_ws, size_t ws_size,
                              hipStream_t stream) {
  const int* unscaled = (const int*)d_in[0];
  const float* scaled = (const float*)d_in[1];
  const float* emb = (const float*)d_in[2];
  const float* W_in = (const float*)d_in[3];
  const float* b_in = (const float*)d_in[4];
  const float* Wih0 = (const float*)d_in[5];
  const float* Whh0 = (const float*)d_in[6];
  const float* bih0 = (const float*)d_in[7];
  const float* bhh0 = (const float*)d_in[8];
  const float* Wih1 = (const float*)d_in[9];
  const float* Whh1 = (const float*)d_in[10];
  const float* bih1 = (const float*)d_in[11];
  const float* bhh1 = (const float*)d_in[12];
  const float* W_out = (const float*)d_in[13];
  const float* b_out = (const float*)d_in[14];
  const float* W_cls = (const float*)d_in[15];
  const float* b_cls = (const float*)d_in[16];

  const size_t o_feat = 0;                       // 23068672
  const size_t o_X = 23068672;                   // 33554432
  const size_t o_WinT = 56623104;                // 360448
  const size_t o_bufA = 56983552;                // 131072
  const size_t o_bufB = 57114624;                // 131072
  const size_t o_flag = 57245696;                // 1024
  const size_t WS_NEED = 57246720;
  if (ws_size < WS_NEED) return;

  char* ws = (char*)d_ws;
  unsigned short* FEAT = (unsigned short*)(ws + o_feat);
  unsigned short* X = (unsigned short*)(ws + o_X);
  unsigned short* W_inT = (unsigned short*)(ws + o_WinT);
  unsigned short* bufA = (unsigned short*)(ws + o_bufA);
  unsigned short* bufB = (unsigned short*)(ws + o_bufB);
  unsigned int* flags = (unsigned int*)(ws + o_flag);
  unsigned int* flagsA = flags;
  unsigned int* flagsB = flags + 128;

  float* out = (float*)d_out;
  float* out_h = out + 77824;
  float* out_c = out + 143360;

  k_init<<<129, 256, 0, stream>>>((unsigned int*)bufB, flags);
  k_prep<<<704, 256, 0, stream>>>(W_in, W_inT);
  k_feat<<<8192, 256, 0, stream>>>(unscaled, scaled, emb, FEAT);
  k_gemm1<<<1024, 256, 0, stream>>>(FEAT, W_inT, b_in, X);
  k_lstm<<<128, 512, 0, stream>>>(Wih0, Whh0, bih0, bhh0, Wih1, Whh1, bih1, bhh1, X, bufA, bufB,
                                  flagsA, flagsB, out_h, out_c);
  k_heads<<<304, 256, 0, stream>>>(out_h, W_out, b_out, W_cls, b_cls, out);
}

// Round 10
// 1685.635 us; speedup vs baseline: 3.3114x; 1.0111x over previous
//
#include <hip/hip_runtime.h>
#include <stdint.h>

#define B_ 128
#define T_ 256
#define F_ 128
#define NCAT_ 32
#define CARD_ 16
#define E_ 8
#define H_ 512
#define INLEN_ 352
#define NCONT_ 96

typedef __bf16 bf16x8 __attribute__((ext_vector_type(8)));
typedef float f32x4 __attribute__((ext_vector_type(4)));
typedef unsigned short ushortx8 __attribute__((ext_vector_type(8)));
typedef unsigned int u32x4 __attribute__((ext_vector_type(4)));   // asm-friendly 128-bit

__device__ __forceinline__ unsigned short f2bf(float f) {
  unsigned int u = __float_as_uint(f);
  u += 0x7fffu + ((u >> 16) & 1u);   // RNE
  return (unsigned short)(u >> 16);
}
__device__ __forceinline__ float sigm(float x) { return 1.0f / (1.0f + __expf(-x)); }
__device__ __forceinline__ float tanhf_(float x) {
  float a = fabsf(x);
  float e = __expf(-2.0f * a);
  float t = (1.0f - e) / (1.0f + e);
  return x < 0.0f ? -t : t;
}

// ---------------- init: zero h buffer B and flags ----------------
__global__ void k_init(unsigned int* bufB_u32, unsigned int* flags) {
  if (blockIdx.x < 128) {
    __hip_atomic_store(&bufB_u32[blockIdx.x * 256 + threadIdx.x], 0u, __ATOMIC_RELAXED,
                       __HIP_MEMORY_SCOPE_AGENT);
  } else {
    __hip_atomic_store(&flags[threadIdx.x], 0u, __ATOMIC_RELAXED, __HIP_MEMORY_SCOPE_AGENT);
  }
}

// ---------------- prep: W_in transposed -> bf16 (512 x 352) ----------------
__global__ void k_prep(const float* __restrict__ W_in, unsigned short* __restrict__ W_inT) {
  int id = blockIdx.x * 256 + threadIdx.x;
  if (id < 512 * INLEN_) {
    int n = id / INLEN_;
    int k = id - n * INLEN_;
    W_inT[id] = f2bf(W_in[k * 512 + n]);
  }
}

// ---------------- features: FEAT[t*128+b][352] bf16 ----------------
__global__ void k_feat(const int* __restrict__ unscaled, const float* __restrict__ scaled,
                       const float* __restrict__ emb, unsigned short* __restrict__ FEAT) {
  int row = blockIdx.x * 4 + (threadIdx.x >> 6);
  int t = row >> 7, b = row & 127;
  const int base = (b * T_ + t) * F_;
  for (int jj = (threadIdx.x & 63); jj < INLEN_; jj += 64) {
    int ci = jj / 11;
    int pos = jj - ci * 11;
    float v;
    if (pos < 8) {
      int cid = unscaled[base + 4 * ci];
      v = emb[(ci * CARD_ + cid) * E_ + pos];
    } else {
      v = scaled[base + 4 * ci + 1 + (pos - 8)];
    }
    FEAT[row * INLEN_ + jj] = f2bf(v);
  }
}

// ---------------- GEMM1: X = relu(FEAT @ W_in + b_in), bf16 out ----------------
__global__ __launch_bounds__(256) void k_gemm1(const unsigned short* __restrict__ FEAT,
                                               const unsigned short* __restrict__ W_inT,
                                               const float* __restrict__ b_in,
                                               unsigned short* __restrict__ X) {
  __shared__ __align__(16) unsigned short As[128 * 40];
  __shared__ __align__(16) unsigned short Bs[128 * 40];
  const int tid = threadIdx.x;
  const int Mtile = blockIdx.x >> 2;
  const int N0 = (blockIdx.x & 3) * 128;
  const int wv = tid >> 6, ln = tid & 63;
  const int lrow = ln & 15, lq = ln >> 4;
  f32x4 acc[2][8];
#pragma unroll
  for (int i = 0; i < 2; ++i)
#pragma unroll
    for (int j = 0; j < 8; ++j) acc[i][j] = (f32x4){0.f, 0.f, 0.f, 0.f};

  for (int kc = 0; kc < 11; ++kc) {
    int k0 = kc * 32;
#pragma unroll
    for (int i = 0; i < 2; ++i) {
      int c = i * 256 + tid;
      int row = c >> 2;
      int col = (c & 3) * 8;
      uint4 va = *(const uint4*)&FEAT[(Mtile * 128 + row) * INLEN_ + k0 + col];
      *(uint4*)&As[row * 40 + col] = va;
      uint4 vb = *(const uint4*)&W_inT[(N0 + row) * INLEN_ + k0 + col];
      *(uint4*)&Bs[row * 40 + col] = vb;
    }
    __syncthreads();
    bf16x8 af[2];
#pragma unroll
    for (int mt = 0; mt < 2; ++mt) {
      int r = wv * 32 + mt * 16 + lrow;
      af[mt] = __builtin_bit_cast(bf16x8, *(const ushortx8*)&As[r * 40 + lq * 8]);
    }
#pragma unroll
    for (int ntl = 0; ntl < 8; ++ntl) {
      bf16x8 bf = __builtin_bit_cast(bf16x8, *(const ushortx8*)&Bs[(ntl * 16 + lrow) * 40 + lq * 8]);
      acc[0][ntl] = __builtin_amdgcn_mfma_f32_16x16x32_bf16(af[0], bf, acc[0][ntl], 0, 0, 0);
      acc[1][ntl] = __builtin_amdgcn_mfma_f32_16x16x32_bf16(af[1], bf, acc[1][ntl], 0, 0, 0);
    }
    __syncthreads();
  }
#pragma unroll
  for (int mt = 0; mt < 2; ++mt)
#pragma unroll
    for (int ntl = 0; ntl < 8; ++ntl) {
      int n = N0 + ntl * 16 + lrow;
      float bias = b_in[n];
#pragma unroll
      for (int r = 0; r < 4; ++r) {
        int row = Mtile * 128 + wv * 32 + mt * 16 + lq * 4 + r;
        float v = acc[mt][ntl][r] + bias;
        v = v > 0.0f ? v : 0.0f;
        X[row * H_ + n] = f2bf(v);
      }
    }
}

// ---------------- persistent LSTM: 8 groups x 16 blocks, 512 thr ----------------
// Protocol = r7 (flags + drain + sleep-throttled wave0 poll; full-line publish /
// consume).  One change vs r7: __launch_bounds__(512) without the min-waves pin.
// The kernel holds 48 bf16x8 weight fragments = 192 VGPRs of persistent state;
// the (512,2) pin capped the allocator at 128 VGPRs -> ~64 regs spilled to
// scratch and reloaded EVERY time-step. An 8-wave workgroup structurally caps
// VGPRs at 256 (1 block/CU; we have 128 blocks for 256 CUs, so packing is
// unchanged) -- dropping the pin lets the weights stay register-resident.
__device__ __forceinline__ void stageX(unsigned short* dst, const unsigned short* src, int tid) {
#pragma unroll
  for (int i = 0; i < 2; ++i) {
    int c = i * 512 + tid;
    int row = c >> 6;
    int col = (c & 63) * 8;
    uint4 v = *(const uint4*)&src[row * H_ + col];
    *(uint4*)&dst[row * 520 + col] = v;
  }
}

__device__ __forceinline__ void stageH(unsigned short* dst, const unsigned short* src, int tid) {
  const int c0 = tid, c1 = 512 + tid;
  const unsigned short* p0 = src + (c0 >> 6) * H_ + (c0 & 63) * 8;
  const unsigned short* p1 = src + (c1 >> 6) * H_ + (c1 & 63) * 8;
  u32x4 v0, v1;
  asm volatile("global_load_dwordx4 %0, %1, off sc0 sc1" : "=v"(v0) : "v"(p0));
  asm volatile("global_load_dwordx4 %0, %1, off sc0 sc1" : "=v"(v1) : "v"(p1));
  asm volatile("s_waitcnt vmcnt(0)" ::: "memory");
  *(u32x4*)&dst[(c0 >> 6) * 520 + (c0 & 63) * 8] = v0;
  *(u32x4*)&dst[(c1 >> 6) * 520 + (c1 & 63) * 8] = v1;
}

// wave0: publish own 16x64B chunk from hS as full lines (4 lanes per 64B line)
__device__ __forceinline__ void publishRows(unsigned short* buf, const unsigned short* hS,
                                            int r0, int j0, int ln) {
  const int r = ln >> 2, q = ln & 3;
  u32x4 v = *(const u32x4*)&hS[r * 520 + j0 + q * 8];
  unsigned short* d = buf + (r0 + r) * H_ + j0 + q * 8;
  asm volatile("global_store_dwordx4 %0, %1, off sc0 sc1" ::"v"(d), "v"(v) : "memory");
}

__device__ __forceinline__ void pollwait(const unsigned int* fp, unsigned int expect, int& guard) {
  for (;;) {
    unsigned int v = __hip_atomic_load(fp, __ATOMIC_RELAXED, __HIP_MEMORY_SCOPE_AGENT);
    if (__all((int)(v >= expect))) break;
    if (++guard > 4000000) break;   // deadlock bail -> wrong answer instead of hang
    __builtin_amdgcn_s_sleep(1);
  }
}

__global__ __launch_bounds__(512) void k_lstm(
    const float* __restrict__ Wih0, const float* __restrict__ Whh0,
    const float* __restrict__ bih0, const float* __restrict__ bhh0,
    const float* __restrict__ Wih1, const float* __restrict__ Whh1,
    const float* __restrict__ bih1, const float* __restrict__ bhh1,
    const unsigned short* __restrict__ X, unsigned short* __restrict__ bufA,
    unsigned short* __restrict__ bufB, unsigned int* flagsA, unsigned int* flagsB,
    float* __restrict__ out_h, float* __restrict__ out_c) {
  __shared__ __align__(16) unsigned short hS[16 * 520];
  __shared__ __align__(16) unsigned short xS[16 * 520];
  __shared__ __align__(16) float gS[128 * 20];
  __shared__ float b0cS[128], b1cS[128];

  const int tid = threadIdx.x;
  const int group = blockIdx.x & 7;    // XCD-packed: group's 16 blocks share an XCD (r2: FETCH/2)
  const int bc = blockIdx.x >> 3;      // 0..15 : h-cols j0..j0+31
  const int j0 = bc * 32;
  const int r0 = group * 16;
  const int wv = tid >> 6, ln = tid & 63;
  const int lrow = ln & 15, lq = ln >> 4;
  const int n_local = wv * 16 + lrow;                              // 0..127 gate-col in block
  const int gcol = ((n_local >> 5) << 9) + j0 + (n_local & 31);    // gate*512 + hcol

  // one-time: weight B-fragments in registers (bf16), combined biases in LDS
  bf16x8 Bf0[32], Bf1[16];
  {
    const float* s0 = Wih0 + gcol * H_;
    const float* s1 = Whh0 + gcol * H_;
#pragma unroll
    for (int ks = 0; ks < 32; ++ks) {
      int k = (ks & 15) * 32 + lq * 8;
      const float* s = (ks < 16) ? (s0 + k) : (s1 + k);
      ushortx8 u;
#pragma unroll
      for (int j = 0; j < 8; ++j) u[j] = f2bf(s[j]);
      Bf0[ks] = __builtin_bit_cast(bf16x8, u);
    }
    const float* sa = Wih1 + gcol * H_;
    const float* sb = Whh1 + gcol * H_;
#pragma unroll
    for (int ks = 0; ks < 16; ++ks) {
      int k = ks * 32 + lq * 8;
      ushortx8 u;
#pragma unroll
      for (int j = 0; j < 8; ++j) u[j] = f2bf(sa[k + j] + sb[k + j]);
      Bf1[ks] = __builtin_bit_cast(bf16x8, u);
    }
  }
  if (tid < 128) {
    int g2 = ((tid >> 5) << 9) + j0 + (tid & 31);
    b0cS[tid] = bih0[g2] + bhh0[g2];
    b1cS[tid] = bih1[g2] + bhh1[g2];
  }

  unsigned int* fA = flagsA + group * 16;
  unsigned int* fB = flagsB + group * 16;
  unsigned int* myA = fA + bc;
  unsigned int* myB = fB + bc;
  const unsigned int* pollA = fA + (ln & 15);
  const unsigned int* pollB = fB + (ln & 15);

  const int eb = tid & 15, ej = tid >> 4;   // elementwise ownership: row eb, h-col j0+ej
  const int fragOff = lrow * 520 + lq * 8;
  float c_reg = 0.0f, cp_v = 0.0f;
  int guard = 0;

  stageX(xS, X + (0 * B_ + r0) * H_, tid);   // preload X_0
  __syncthreads();

#pragma unroll 1
  for (int t = 0; t < T_; ++t) {
    // ======== cell 0 ========
    f32x4 acc0 = (f32x4){0.f, 0.f, 0.f, 0.f};
    f32x4 acc1 = (f32x4){0.f, 0.f, 0.f, 0.f};
#pragma unroll
    for (int ks = 0; ks < 16; ks += 2) {   // x-part: independent of peers -> before poll
      bf16x8 a0 = __builtin_bit_cast(bf16x8, *(const ushortx8*)&xS[fragOff + ks * 32]);
      acc0 = __builtin_amdgcn_mfma_f32_16x16x32_bf16(a0, Bf0[ks], acc0, 0, 0, 0);
      bf16x8 a1 = __builtin_bit_cast(bf16x8, *(const ushortx8*)&xS[fragOff + (ks + 1) * 32]);
      acc1 = __builtin_amdgcn_mfma_f32_16x16x32_bf16(a1, Bf0[ks + 1], acc1, 0, 0, 0);
    }
    if (wv == 0) pollwait(pollB, (unsigned int)t, guard);   // h1_{t-1} ready (t=0 trivial)
    __builtin_amdgcn_s_barrier();
    stageH(hS, bufB + r0 * H_, tid);
    __syncthreads();
#pragma unroll
    for (int ks = 0; ks < 16; ks += 2) {
      bf16x8 a0 = __builtin_bit_cast(bf16x8, *(const ushortx8*)&hS[fragOff + ks * 32]);
      acc0 = __builtin_amdgcn_mfma_f32_16x16x32_bf16(a0, Bf0[16 + ks], acc0, 0, 0, 0);
      bf16x8 a1 = __builtin_bit_cast(bf16x8, *(const ushortx8*)&hS[fragOff + (ks + 1) * 32]);
      acc1 = __builtin_amdgcn_mfma_f32_16x16x32_bf16(a1, Bf0[16 + ks + 1], acc1, 0, 0, 0);
    }
    *(f32x4*)&gS[n_local * 20 + lq * 4] = acc0 + acc1;
    __syncthreads();
    {
      float iv = gS[(ej) * 20 + eb] + b0cS[ej];
      float fv = gS[(32 + ej) * 20 + eb] + b0cS[32 + ej];
      float gv = gS[(64 + ej) * 20 + eb] + b0cS[64 + ej];
      float ov = gS[(96 + ej) * 20 + eb] + b0cS[96 + ej];
      cp_v = sigm(fv) * c_reg + sigm(iv) * tanhf_(gv);
      float hv = sigm(ov) * tanhf_(cp_v);
      hS[eb * 520 + j0 + ej] = f2bf(hv);   // marshal own h through LDS
    }
    __syncthreads();   // hS own-chunk complete for wave0 marshal
    if (wv == 0) {
      publishRows(bufA, hS, r0, j0, ln);                     // full-line stores, no RMW
      asm volatile("s_waitcnt vmcnt(0)" ::: "memory");       // data acked at coherence point
      if (ln == 0) __hip_atomic_store(myA, (unsigned int)(t + 1), __ATOMIC_RELAXED,
                                      __HIP_MEMORY_SCOPE_AGENT);
    }

    // ======== cell 1 ========
    if (t + 1 < T_) stageX(xS, X + ((t + 1) * B_ + r0) * H_, tid);   // prefetch next X
    if (wv == 0) pollwait(pollA, (unsigned int)(t + 1), guard);
    __builtin_amdgcn_s_barrier();
    stageH(hS, bufA + r0 * H_, tid);
    __syncthreads();
    acc0 = (f32x4){0.f, 0.f, 0.f, 0.f};
    acc1 = (f32x4){0.f, 0.f, 0.f, 0.f};
#pragma unroll
    for (int ks = 0; ks < 16; ks += 2) {
      bf16x8 a0 = __builtin_bit_cast(bf16x8, *(const ushortx8*)&hS[fragOff + ks * 32]);
      acc0 = __builtin_amdgcn_mfma_f32_16x16x32_bf16(a0, Bf1[ks], acc0, 0, 0, 0);
      bf16x8 a1 = __builtin_bit_cast(bf16x8, *(const ushortx8*)&hS[fragOff + (ks + 1) * 32]);
      acc1 = __builtin_amdgcn_mfma_f32_16x16x32_bf16(a1, Bf1[ks + 1], acc1, 0, 0, 0);
    }
    *(f32x4*)&gS[n_local * 20 + lq * 4] = acc0 + acc1;
    __syncthreads();
    {
      float iv = gS[(ej) * 20 + eb] + b1cS[ej];
      float fv = gS[(32 + ej) * 20 + eb] + b1cS[32 + ej];
      float gv = gS[(64 + ej) * 20 + eb] + b1cS[64 + ej];
      float ov = gS[(96 + ej) * 20 + eb] + b1cS[96 + ej];
      float cn = sigm(fv) * cp_v + sigm(iv) * tanhf_(gv);
      float hv = sigm(ov) * tanhf_(cn);
      c_reg = cn;
      hS[eb * 520 + j0 + ej] = f2bf(hv);
      if (t == T_ - 1) {
        out_h[(r0 + eb) * H_ + j0 + ej] = hv;
        out_c[(r0 + eb) * H_ + j0 + ej] = cn;
      }
    }
    __syncthreads();
    if (wv == 0) {
      publishRows(bufB, hS, r0, j0, ln);
      asm volatile("s_waitcnt vmcnt(0)" ::: "memory");
      if (ln == 0) __hip_atomic_store(myB, (unsigned int)(t + 1), __ATOMIC_RELAXED,
                                      __HIP_MEMORY_SCOPE_AGENT);
    }
  }
}

// ---------------- heads: cont_out + cls_out (f32) ----------------
__global__ __launch_bounds__(256) void k_heads(const float* __restrict__ h,
                                               const float* __restrict__ W_out,
                                               const float* __restrict__ b_out,
                                               const float* __restrict__ W_cls,
                                               const float* __restrict__ b_cls,
                                               float* __restrict__ out) {
  int o = blockIdx.x * 256 + threadIdx.x;
  if (o < B_ * NCONT_) {
    int b = o / NCONT_;
    int n = o - b * NCONT_;
    float acc = b_out[n];
    const float* hb = h + b * H_;
    for (int k = 0; k < H_; k += 4) {
      acc += hb[k] * W_out[k * NCONT_ + n] + hb[k + 1] * W_out[(k + 1) * NCONT_ + n] +
             hb[k + 2] * W_out[(k + 2) * NCONT_ + n] + hb[k + 3] * W_out[(k + 3) * NCONT_ + n];
    }
    out[o] = acc;
  } else {
    int oo = o - B_ * NCONT_;
    int b = oo >> 9;
    int r = oo & 511;
    int ci = r >> 4, cd = r & 15;
    float acc = b_cls[ci * 16 + cd];
    const float* hb = h + b * H_;
    const float* wc = W_cls + ci * 512 * 16 + cd;
    for (int k = 0; k < H_; k += 4) {
      acc += hb[k] * wc[k * 16] + hb[k + 1] * wc[(k + 1) * 16] + hb[k + 2] * wc[(k + 2) * 16] +
             hb[k + 3] * wc[(k + 3) * 16];
    }
    out[B_ * NCONT_ + oo] = acc;
  }
}

extern "C" void kernel_launch(void* const* d_in, const int* in_sizes, int n_in,
                              void* d_out, int out_size, void* d_ws, size_t ws_size,
                              hipStream_t stream) {
  const int* unscaled = (const int*)d_in[0];
  const float* scaled = (const float*)d_in[1];
  const float* emb = (const float*)d_in[2];
  const float* W_in = (const float*)d_in[3];
  const float* b_in = (const float*)d_in[4];
  const float* Wih0 = (const float*)d_in[5];
  const float* Whh0 = (const float*)d_in[6];
  const float* bih0 = (const float*)d_in[7];
  const float* bhh0 = (const float*)d_in[8];
  const float* Wih1 = (const float*)d_in[9];
  const float* Whh1 = (const float*)d_in[10];
  const float* bih1 = (const float*)d_in[11];
  const float* bhh1 = (const float*)d_in[12];
  const float* W_out = (const float*)d_in[13];
  const float* b_out = (const float*)d_in[14];
  const float* W_cls = (const float*)d_in[15];
  const float* b_cls = (const float*)d_in[16];

  const size_t o_feat = 0;                       // 23068672
  const size_t o_X = 23068672;                   // 33554432
  const size_t o_WinT = 56623104;                // 360448
  const size_t o_bufA = 56983552;                // 131072
  const size_t o_bufB = 57114624;                // 131072
  const size_t o_flag = 57245696;                // 1024
  const size_t WS_NEED = 57246720;
  if (ws_size < WS_NEED) return;

  char* ws = (char*)d_ws;
  unsigned short* FEAT = (unsigned short*)(ws + o_feat);
  unsigned short* X = (unsigned short*)(ws + o_X);
  unsigned short* W_inT = (unsigned short*)(ws + o_WinT);
  unsigned short* bufA = (unsigned short*)(ws + o_bufA);
  unsigned short* bufB = (unsigned short*)(ws + o_bufB);
  unsigned int* flags = (unsigned int*)(ws + o_flag);
  unsigned int* flagsA = flags;
  unsigned int* flagsB = flags + 128;

  float* out = (float*)d_out;
  float* out_h = out + 77824;
  float* out_c = out + 143360;

  k_init<<<129, 256, 0, stream>>>((unsigned int*)bufB, flags);
  k_prep<<<704, 256, 0, stream>>>(W_in, W_inT);
  k_feat<<<8192, 256, 0, stream>>>(unscaled, scaled, emb, FEAT);
  k_gemm1<<<1024, 256, 0, stream>>>(FEAT, W_inT, b_in, X);
  k_lstm<<<128, 512, 0, stream>>>(Wih0, Whh0, bih0, bhh0, Wih1, Whh1, bih1, bhh1, X, bufA, bufB,
                                  flagsA, flagsB, out_h, out_c);
  k_heads<<<304, 256, 0, stream>>>(out_h, W_out, b_out, W_cls, b_cls, out);
}

// Round 12
// 1679.677 us; speedup vs baseline: 3.3232x; 1.0035x over previous
//
#include <hip/hip_runtime.h>
#include <stdint.h>

#define B_ 128
#define T_ 256
#define F_ 128
#define NCAT_ 32
#define CARD_ 16
#define E_ 8
#define H_ 512
#define INLEN_ 352
#define NCONT_ 96

typedef __bf16 bf16x8 __attribute__((ext_vector_type(8)));
typedef float f32x4 __attribute__((ext_vector_type(4)));
typedef unsigned short ushortx8 __attribute__((ext_vector_type(8)));
typedef unsigned int u32x4 __attribute__((ext_vector_type(4)));   // asm-friendly 128-bit

__device__ __forceinline__ unsigned short f2bf(float f) {
  unsigned int u = __float_as_uint(f);
  u += 0x7fffu + ((u >> 16) & 1u);   // RNE
  return (unsigned short)(u >> 16);
}
__device__ __forceinline__ float sigm(float x) { return 1.0f / (1.0f + __expf(-x)); }
__device__ __forceinline__ float tanhf_(float x) {
  float a = fabsf(x);
  float e = __expf(-2.0f * a);
  float t = (1.0f - e) / (1.0f + e);
  return x < 0.0f ? -t : t;
}

// ---------------- init: zero h buffer B and flags ----------------
__global__ void k_init(unsigned int* bufB_u32, unsigned int* flags) {
  if (blockIdx.x < 128) {
    __hip_atomic_store(&bufB_u32[blockIdx.x * 256 + threadIdx.x], 0u, __ATOMIC_RELAXED,
                       __HIP_MEMORY_SCOPE_AGENT);
  } else {
    __hip_atomic_store(&flags[threadIdx.x], 0u, __ATOMIC_RELAXED, __HIP_MEMORY_SCOPE_AGENT);
  }
}

// ---------------- prep: W_in transposed -> bf16 (512 x 352) ----------------
__global__ void k_prep(const float* __restrict__ W_in, unsigned short* __restrict__ W_inT) {
  int id = blockIdx.x * 256 + threadIdx.x;
  if (id < 512 * INLEN_) {
    int n = id / INLEN_;
    int k = id - n * INLEN_;
    W_inT[id] = f2bf(W_in[k * 512 + n]);
  }
}

// ---------------- features: FEAT[t*128+b][352] bf16 ----------------
__global__ void k_feat(const int* __restrict__ unscaled, const float* __restrict__ scaled,
                       const float* __restrict__ emb, unsigned short* __restrict__ FEAT) {
  int row = blockIdx.x * 4 + (threadIdx.x >> 6);
  int t = row >> 7, b = row & 127;
  const int base = (b * T_ + t) * F_;
  for (int jj = (threadIdx.x & 63); jj < INLEN_; jj += 64) {
    int ci = jj / 11;
    int pos = jj - ci * 11;
    float v;
    if (pos < 8) {
      int cid = unscaled[base + 4 * ci];
      v = emb[(ci * CARD_ + cid) * E_ + pos];
    } else {
      v = scaled[base + 4 * ci + 1 + (pos - 8)];
    }
    FEAT[row * INLEN_ + jj] = f2bf(v);
  }
}

// ---------------- GEMM1: X = relu(FEAT @ W_in + b_in), bf16 out ----------------
__global__ __launch_bounds__(256) void k_gemm1(const unsigned short* __restrict__ FEAT,
                                               const unsigned short* __restrict__ W_inT,
                                               const float* __restrict__ b_in,
                                               unsigned short* __restrict__ X) {
  __shared__ __align__(16) unsigned short As[128 * 40];
  __shared__ __align__(16) unsigned short Bs[128 * 40];
  const int tid = threadIdx.x;
  const int Mtile = blockIdx.x >> 2;
  const int N0 = (blockIdx.x & 3) * 128;
  const int wv = tid >> 6, ln = tid & 63;
  const int lrow = ln & 15, lq = ln >> 4;
  f32x4 acc[2][8];
#pragma unroll
  for (int i = 0; i < 2; ++i)
#pragma unroll
    for (int j = 0; j < 8; ++j) acc[i][j] = (f32x4){0.f, 0.f, 0.f, 0.f};

  for (int kc = 0; kc < 11; ++kc) {
    int k0 = kc * 32;
#pragma unroll
    for (int i = 0; i < 2; ++i) {
      int c = i * 256 + tid;
      int row = c >> 2;
      int col = (c & 3) * 8;
      uint4 va = *(const uint4*)&FEAT[(Mtile * 128 + row) * INLEN_ + k0 + col];
      *(uint4*)&As[row * 40 + col] = va;
      uint4 vb = *(const uint4*)&W_inT[(N0 + row) * INLEN_ + k0 + col];
      *(uint4*)&Bs[row * 40 + col] = vb;
    }
    __syncthreads();
    bf16x8 af[2];
#pragma unroll
    for (int mt = 0; mt < 2; ++mt) {
      int r = wv * 32 + mt * 16 + lrow;
      af[mt] = __builtin_bit_cast(bf16x8, *(const ushortx8*)&As[r * 40 + lq * 8]);
    }
#pragma unroll
    for (int ntl = 0; ntl < 8; ++ntl) {
      bf16x8 bf = __builtin_bit_cast(bf16x8, *(const ushortx8*)&Bs[(ntl * 16 + lrow) * 40 + lq * 8]);
      acc[0][ntl] = __builtin_amdgcn_mfma_f32_16x16x32_bf16(af[0], bf, acc[0][ntl], 0, 0, 0);
      acc[1][ntl] = __builtin_amdgcn_mfma_f32_16x16x32_bf16(af[1], bf, acc[1][ntl], 0, 0, 0);
    }
    __syncthreads();
  }
#pragma unroll
  for (int mt = 0; mt < 2; ++mt)
#pragma unroll
    for (int ntl = 0; ntl < 8; ++ntl) {
      int n = N0 + ntl * 16 + lrow;
      float bias = b_in[n];
#pragma unroll
      for (int r = 0; r < 4; ++r) {
        int row = Mtile * 128 + wv * 32 + mt * 16 + lq * 4 + r;
        float v = acc[mt][ntl][r] + bias;
        v = v > 0.0f ? v : 0.0f;
        X[row * H_ + n] = f2bf(v);
      }
    }
}

// ---------------- persistent LSTM: 8 groups x 16 blocks, 512 thr ----------------
// Protocol = r7/r10 (flags + drain + sleep-throttled poll; full-line publish /
// consume). One change vs r10: PRODUCER/CONSUMER WAVE SPLIT -- wave1 does
// publish+drain+flag while wave0 polls the incoming flags. The outgoing
// store-ack drain (~1 RTT) now overlaps the incoming detect instead of
// serializing in front of it. Protocol semantics are byte-identical (same
// stores, same drain-before-flag order, same poll, same barriers); only the
// wave assignment changed. The poll waits on all 16 flags incl. our own,
// which wave1 sets concurrently -- the s_barrier after the poll joins them.
__device__ __forceinline__ void stageX(unsigned short* dst, const unsigned short* src, int tid) {
#pragma unroll
  for (int i = 0; i < 2; ++i) {
    int c = i * 512 + tid;
    int row = c >> 6;
    int col = (c & 63) * 8;
    uint4 v = *(const uint4*)&src[row * H_ + col];
    *(uint4*)&dst[row * 520 + col] = v;
  }
}

__device__ __forceinline__ void stageH(unsigned short* dst, const unsigned short* src, int tid) {
  const int c0 = tid, c1 = 512 + tid;
  const unsigned short* p0 = src + (c0 >> 6) * H_ + (c0 & 63) * 8;
  const unsigned short* p1 = src + (c1 >> 6) * H_ + (c1 & 63) * 8;
  u32x4 v0, v1;
  asm volatile("global_load_dwordx4 %0, %1, off sc0 sc1" : "=v"(v0) : "v"(p0));
  asm volatile("global_load_dwordx4 %0, %1, off sc0 sc1" : "=v"(v1) : "v"(p1));
  asm volatile("s_waitcnt vmcnt(0)" ::: "memory");
  *(u32x4*)&dst[(c0 >> 6) * 520 + (c0 & 63) * 8] = v0;
  *(u32x4*)&dst[(c1 >> 6) * 520 + (c1 & 63) * 8] = v1;
}

// producer wave: publish own 16x64B chunk from hS as full lines (4 lanes/line)
__device__ __forceinline__ void publishRows(unsigned short* buf, const unsigned short* hS,
                                            int r0, int j0, int ln) {
  const int r = ln >> 2, q = ln & 3;
  u32x4 v = *(const u32x4*)&hS[r * 520 + j0 + q * 8];
  unsigned short* d = buf + (r0 + r) * H_ + j0 + q * 8;
  asm volatile("global_store_dwordx4 %0, %1, off sc0 sc1" ::"v"(d), "v"(v) : "memory");
}

__device__ __forceinline__ void pollwait(const unsigned int* fp, unsigned int expect, int& guard) {
  for (;;) {
    unsigned int v = __hip_atomic_load(fp, __ATOMIC_RELAXED, __HIP_MEMORY_SCOPE_AGENT);
    if (__all((int)(v >= expect))) break;
    if (++guard > 4000000) break;   // deadlock bail -> wrong answer instead of hang
    __builtin_amdgcn_s_sleep(1);
  }
}

__global__ __launch_bounds__(512) void k_lstm(
    const float* __restrict__ Wih0, const float* __restrict__ Whh0,
    const float* __restrict__ bih0, const float* __restrict__ bhh0,
    const float* __restrict__ Wih1, const float* __restrict__ Whh1,
    const float* __restrict__ bih1, const float* __restrict__ bhh1,
    const unsigned short* __restrict__ X, unsigned short* __restrict__ bufA,
    unsigned short* __restrict__ bufB, unsigned int* flagsA, unsigned int* flagsB,
    float* __restrict__ out_h, float* __restrict__ out_c) {
  __shared__ __align__(16) unsigned short hS[16 * 520];
  __shared__ __align__(16) unsigned short xS[16 * 520];
  __shared__ __align__(16) float gS[128 * 20];
  __shared__ float b0cS[128], b1cS[128];

  const int tid = threadIdx.x;
  const int group = blockIdx.x & 7;    // XCD-packed: group's 16 blocks share an XCD (r2: FETCH/2)
  const int bc = blockIdx.x >> 3;      // 0..15 : h-cols j0..j0+31
  const int j0 = bc * 32;
  const int r0 = group * 16;
  const int wv = tid >> 6, ln = tid & 63;
  const int lrow = ln & 15, lq = ln >> 4;
  const int n_local = wv * 16 + lrow;                              // 0..127 gate-col in block
  const int gcol = ((n_local >> 5) << 9) + j0 + (n_local & 31);    // gate*512 + hcol

  // one-time: weight B-fragments in registers (bf16), combined biases in LDS
  bf16x8 Bf0[32], Bf1[16];
  {
    const float* s0 = Wih0 + gcol * H_;
    const float* s1 = Whh0 + gcol * H_;
#pragma unroll
    for (int ks = 0; ks < 32; ++ks) {
      int k = (ks & 15) * 32 + lq * 8;
      const float* s = (ks < 16) ? (s0 + k) : (s1 + k);
      ushortx8 u;
#pragma unroll
      for (int j = 0; j < 8; ++j) u[j] = f2bf(s[j]);
      Bf0[ks] = __builtin_bit_cast(bf16x8, u);
    }
    const float* sa = Wih1 + gcol * H_;
    const float* sb = Whh1 + gcol * H_;
#pragma unroll
    for (int ks = 0; ks < 16; ++ks) {
      int k = ks * 32 + lq * 8;
      ushortx8 u;
#pragma unroll
      for (int j = 0; j < 8; ++j) u[j] = f2bf(sa[k + j] + sb[k + j]);
      Bf1[ks] = __builtin_bit_cast(bf16x8, u);
    }
  }
  if (tid < 128) {
    int g2 = ((tid >> 5) << 9) + j0 + (tid & 31);
    b0cS[tid] = bih0[g2] + bhh0[g2];
    b1cS[tid] = bih1[g2] + bhh1[g2];
  }

  unsigned int* fA = flagsA + group * 16;
  unsigned int* fB = flagsB + group * 16;
  unsigned int* myA = fA + bc;
  unsigned int* myB = fB + bc;
  const unsigned int* pollA = fA + (ln & 15);
  const unsigned int* pollB = fB + (ln & 15);

  const int eb = tid & 15, ej = tid >> 4;   // elementwise ownership: row eb, h-col j0+ej
  const int fragOff = lrow * 520 + lq * 8;
  float c_reg = 0.0f, cp_v = 0.0f;
  int guard = 0;

  stageX(xS, X + (0 * B_ + r0) * H_, tid);   // preload X_0
  __syncthreads();

#pragma unroll 1
  for (int t = 0; t < T_; ++t) {
    // ======== cell 0 ========
    f32x4 acc0 = (f32x4){0.f, 0.f, 0.f, 0.f};
    f32x4 acc1 = (f32x4){0.f, 0.f, 0.f, 0.f};
#pragma unroll
    for (int ks = 0; ks < 16; ks += 2) {   // x-part: independent of peers -> before poll
      bf16x8 a0 = __builtin_bit_cast(bf16x8, *(const ushortx8*)&xS[fragOff + ks * 32]);
      acc0 = __builtin_amdgcn_mfma_f32_16x16x32_bf16(a0, Bf0[ks], acc0, 0, 0, 0);
      bf16x8 a1 = __builtin_bit_cast(bf16x8, *(const ushortx8*)&xS[fragOff + (ks + 1) * 32]);
      acc1 = __builtin_amdgcn_mfma_f32_16x16x32_bf16(a1, Bf0[ks + 1], acc1, 0, 0, 0);
    }
    if (wv == 0) pollwait(pollB, (unsigned int)t, guard);   // h1_{t-1} ready (t=0 trivial)
    __builtin_amdgcn_s_barrier();
    stageH(hS, bufB + r0 * H_, tid);
    __syncthreads();
#pragma unroll
    for (int ks = 0; ks < 16; ks += 2) {
      bf16x8 a0 = __builtin_bit_cast(bf16x8, *(const ushortx8*)&hS[fragOff + ks * 32]);
      acc0 = __builtin_amdgcn_mfma_f32_16x16x32_bf16(a0, Bf0[16 + ks], acc0, 0, 0, 0);
      bf16x8 a1 = __builtin_bit_cast(bf16x8, *(const ushortx8*)&hS[fragOff + (ks + 1) * 32]);
      acc1 = __builtin_amdgcn_mfma_f32_16x16x32_bf16(a1, Bf0[16 + ks + 1], acc1, 0, 0, 0);
    }
    *(f32x4*)&gS[n_local * 20 + lq * 4] = acc0 + acc1;
    __syncthreads();
    {
      float iv = gS[(ej) * 20 + eb] + b0cS[ej];
      float fv = gS[(32 + ej) * 20 + eb] + b0cS[32 + ej];
      float gv = gS[(64 + ej) * 20 + eb] + b0cS[64 + ej];
      float ov = gS[(96 + ej) * 20 + eb] + b0cS[96 + ej];
      cp_v = sigm(fv) * c_reg + sigm(iv) * tanhf_(gv);
      float hv = sigm(ov) * tanhf_(cp_v);
      hS[eb * 520 + j0 + ej] = f2bf(hv);   // marshal own h through LDS
    }
    __syncthreads();   // hS own-chunk complete for the producer wave
    // -- producer wave (1): publish+drain+flag; overlaps consumer wave (0)'s poll --
    if (wv == 1) {
      publishRows(bufA, hS, r0, j0, ln);                     // full-line stores, no RMW
      asm volatile("s_waitcnt vmcnt(0)" ::: "memory");       // data acked at coherence point
      if (ln == 0) __hip_atomic_store(myA, (unsigned int)(t + 1), __ATOMIC_RELAXED,
                                      __HIP_MEMORY_SCOPE_AGENT);
    }

    // ======== cell 1 ========
    if (t + 1 < T_) stageX(xS, X + ((t + 1) * B_ + r0) * H_, tid);   // prefetch next X
    if (wv == 0) pollwait(pollA, (unsigned int)(t + 1), guard);
    __builtin_amdgcn_s_barrier();
    stageH(hS, bufA + r0 * H_, tid);
    __syncthreads();
    acc0 = (f32x4){0.f, 0.f, 0.f, 0.f};
    acc1 = (f32x4){0.f, 0.f, 0.f, 0.f};
#pragma unroll
    for (int ks = 0; ks < 16; ks += 2) {
      bf16x8 a0 = __builtin_bit_cast(bf16x8, *(const ushortx8*)&hS[fragOff + ks * 32]);
      acc0 = __builtin_amdgcn_mfma_f32_16x16x32_bf16(a0, Bf1[ks], acc0, 0, 0, 0);
      bf16x8 a1 = __builtin_bit_cast(bf16x8, *(const ushortx8*)&hS[fragOff + (ks + 1) * 32]);
      acc1 = __builtin_amdgcn_mfma_f32_16x16x32_bf16(a1, Bf1[ks + 1], acc1, 0, 0, 0);
    }
    *(f32x4*)&gS[n_local * 20 + lq * 4] = acc0 + acc1;
    __syncthreads();
    {
      float iv = gS[(ej) * 20 + eb] + b1cS[ej];
      float fv = gS[(32 + ej) * 20 + eb] + b1cS[32 + ej];
      float gv = gS[(64 + ej) * 20 + eb] + b1cS[64 + ej];
      float ov = gS[(96 + ej) * 20 + eb] + b1cS[96 + ej];
      float cn = sigm(fv) * cp_v + sigm(iv) * tanhf_(gv);
      float hv = sigm(ov) * tanhf_(cn);
      c_reg = cn;
      hS[eb * 520 + j0 + ej] = f2bf(hv);
      if (t == T_ - 1) {
        out_h[(r0 + eb) * H_ + j0 + ej] = hv;
        out_c[(r0 + eb) * H_ + j0 + ej] = cn;
      }
    }
    __syncthreads();
    if (wv == 1) {
      publishRows(bufB, hS, r0, j0, ln);
      asm volatile("s_waitcnt vmcnt(0)" ::: "memory");
      if (ln == 0) __hip_atomic_store(myB, (unsigned int)(t + 1), __ATOMIC_RELAXED,
                                      __HIP_MEMORY_SCOPE_AGENT);
    }
  }
}

// ---------------- heads: cont_out + cls_out (f32) ----------------
__global__ __launch_bounds__(256) void k_heads(const float* __restrict__ h,
                                               const float* __restrict__ W_out,
                                               const float* __restrict__ b_out,
                                               const float* __restrict__ W_cls,
                                               const float* __restrict__ b_cls,
                                               float* __restrict__ out) {
  int o = blockIdx.x * 256 + threadIdx.x;
  if (o < B_ * NCONT_) {
    int b = o / NCONT_;
    int n = o - b * NCONT_;
    float acc = b_out[n];
    const float* hb = h + b * H_;
    for (int k = 0; k < H_; k += 4) {
      acc += hb[k] * W_out[k * NCONT_ + n] + hb[k + 1] * W_out[(k + 1) * NCONT_ + n] +
             hb[k + 2] * W_out[(k + 2) * NCONT_ + n] + hb[k + 3] * W_out[(k + 3) * NCONT_ + n];
    }
    out[o] = acc;
  } else {
    int oo = o - B_ * NCONT_;
    int b = oo >> 9;
    int r = oo & 511;
    int ci = r >> 4, cd = r & 15;
    float acc = b_cls[ci * 16 + cd];
    const float* hb = h + b * H_;
    const float* wc = W_cls + ci * 512 * 16 + cd;
    for (int k = 0; k < H_; k += 4) {
      acc += hb[k] * wc[k * 16] + hb[k + 1] * wc[(k + 1) * 16] + hb[k + 2] * wc[(k + 2) * 16] +
             hb[k + 3] * wc[(k + 3) * 16];
    }
    out[B_ * NCONT_ + oo] = acc;
  }
}

extern "C" void kernel_launch(void* const* d_in, const int* in_sizes, int n_in,
                              void* d_out, int out_size, void* d_ws, size_t ws_size,
                              hipStream_t stream) {
  const int* unscaled = (const int*)d_in[0];
  const float* scaled = (const float*)d_in[1];
  const float* emb = (const float*)d_in[2];
  const float* W_in = (const float*)d_in[3];
  const float* b_in = (const float*)d_in[4];
  const float* Wih0 = (const float*)d_in[5];
  const float* Whh0 = (const float*)d_in[6];
  const float* bih0 = (const float*)d_in[7];
  const float* bhh0 = (const float*)d_in[8];
  const float* Wih1 = (const float*)d_in[9];
  const float* Whh1 = (const float*)d_in[10];
  const float* bih1 = (const float*)d_in[11];
  const float* bhh1 = (const float*)d_in[12];
  const float* W_out = (const float*)d_in[13];
  const float* b_out = (const float*)d_in[14];
  const float* W_cls = (const float*)d_in[15];
  const float* b_cls = (const float*)d_in[16];

  const size_t o_feat = 0;                       // 23068672
  const size_t o_X = 23068672;                   // 33554432
  const size_t o_WinT = 56623104;                // 360448
  const size_t o_bufA = 56983552;                // 131072
  const size_t o_bufB = 57114624;                // 131072
  const size_t o_flag = 57245696;                // 1024
  const size_t WS_NEED = 57246720;
  if (ws_size < WS_NEED) return;

  char* ws = (char*)d_ws;
  unsigned short* FEAT = (unsigned short*)(ws + o_feat);
  unsigned short* X = (unsigned short*)(ws + o_X);
  unsigned short* W_inT = (unsigned short*)(ws + o_WinT);
  unsigned short* bufA = (unsigned short*)(ws + o_bufA);
  unsigned short* bufB = (unsigned short*)(ws + o_bufB);
  unsigned int* flags = (unsigned int*)(ws + o_flag);
  unsigned int* flagsA = flags;
  unsigned int* flagsB = flags + 128;

  float* out = (float*)d_out;
  float* out_h = out + 77824;
  float* out_c = out + 143360;

  k_init<<<129, 256, 0, stream>>>((unsigned int*)bufB, flags);
  k_prep<<<704, 256, 0, stream>>>(W_in, W_inT);
  k_feat<<<8192, 256, 0, stream>>>(unscaled, scaled, emb, FEAT);
  k_gemm1<<<1024, 256, 0, stream>>>(FEAT, W_inT, b_in, X);
  k_lstm<<<128, 512, 0, stream>>>(Wih0, Whh0, bih0, bhh0, Wih1, Whh1, bih1, bhh1, X, bufA, bufB,
                                  flagsA, flagsB, out_h, out_c);
  k_heads<<<304, 256, 0, stream>>>(out_h, W_out, b_out, W_cls, b_cls, out);
}